// Round 12
// baseline (526.418 us; speedup 1.0000x reference)
//
#include <hip/hip_runtime.h>
#include <math.h>

#define N_NODESC 50000
#define NPAD 50048              // 782 * 64
#define N_EDGESC 800000
#define N_GRAPHSC 64
#define IN_DIMC 128
#define HIDC 256
#define N_LAYERSC 4
#define EPSV 1e-12f

#define NBUCK 196               // buckets of 256 nodes
#define EPB 4096
#define NBLK1 196               // ceil(800000/4096)

typedef __attribute__((ext_vector_type(8))) short short8;
typedef __attribute__((ext_vector_type(4))) float floatx4;
typedef __attribute__((ext_vector_type(2))) float floatx2;

__device__ __forceinline__ unsigned short f2b(float f) {
    union { float f; unsigned u; } v; v.f = f;
    unsigned r = v.u + 0x7FFFu + ((v.u >> 16) & 1u);
    return (unsigned short)(r >> 16);
}
__device__ __forceinline__ float blo(unsigned u) { return __uint_as_float(u << 16); }
__device__ __forceinline__ float bhi(unsigned u) { return __uint_as_float(u & 0xFFFF0000u); }
__device__ __forceinline__ unsigned pkb(float a, float b) {
    return (unsigned)f2b(a) | ((unsigned)f2b(b) << 16);
}
__device__ __forceinline__ float b2f(unsigned short s) {
    return __uint_as_float((unsigned)s << 16);
}
__device__ __forceinline__ unsigned char f2q(float v) {
    return (unsigned char)(__builtin_amdgcn_cvt_pk_fp8_f32(v, v, 0, false) & 0xFF);
}
__device__ __forceinline__ void ldscp16(const void* g, void* l) {
    __builtin_amdgcn_global_load_lds(
        (const __attribute__((address_space(1))) unsigned int*)g,
        (__attribute__((address_space(3))) unsigned int*)l, 16, 0, 0);
}

// ---------------- graph boundaries via binary search (gid sorted) ----------------
__global__ __launch_bounds__(128) void k_gbounds(const int* __restrict__ gid,
        int* __restrict__ gstart) {
    int g = threadIdx.x;
    if (g > N_GRAPHSC) return;
    int lo = 0, hi = N_NODESC;
    while (lo < hi) {
        int mid = (lo + hi) >> 1;
        if (gid[mid] < g) lo = mid + 1; else hi = mid;
    }
    gstart[g] = lo;
}

// ---------------- CSR build, bucketed (bucket = dst>>8) ----------------
__global__ __launch_bounds__(256) void k_bcount(const int* __restrict__ dst,
        int* __restrict__ gbcnt) {
    __shared__ int bc[256];
    int t = threadIdx.x;
    bc[t] = 0;
    __syncthreads();
    int e0 = blockIdx.x * EPB;
    for (int i = t; i < EPB; i += 256) {
        int e = e0 + i;
        if (e < N_EDGESC) atomicAdd(&bc[dst[e] >> 8], 1);
    }
    __syncthreads();
    if (t < NBUCK && bc[t] > 0) atomicAdd(&gbcnt[t], bc[t]);
}

__global__ __launch_bounds__(256) void k_bscan(const int* __restrict__ gbcnt,
        int* __restrict__ boffB, int* __restrict__ gcurB) {
    __shared__ int s[256];
    int t = threadIdx.x;
    int v = (t < NBUCK) ? gbcnt[t] : 0;
    s[t] = v;
    __syncthreads();
    for (int d = 1; d < 256; d <<= 1) {
        int u = (t >= d) ? s[t - d] : 0;
        __syncthreads();
        s[t] += u;
        __syncthreads();
    }
    if (t < NBUCK) {
        int excl = s[t] - v;
        boffB[t] = excl;
        gcurB[t] = excl;
    }
    if (t == 0) boffB[NBUCK] = N_EDGESC;
}

__global__ __launch_bounds__(256) void k_bscatter(const int* __restrict__ src,
        const int* __restrict__ dst, int* __restrict__ gcurB,
        unsigned* __restrict__ ebpack) {
    __shared__ int bc[256];
    __shared__ int cur[256];
    int t = threadIdx.x;
    bc[t] = 0;
    __syncthreads();
    int e0 = blockIdx.x * EPB;
    for (int i = t; i < EPB; i += 256) {
        int e = e0 + i;
        if (e < N_EDGESC) atomicAdd(&bc[dst[e] >> 8], 1);
    }
    __syncthreads();
    if (t < NBUCK)
        cur[t] = (bc[t] > 0) ? atomicAdd(&gcurB[t], bc[t]) : 0;
    __syncthreads();
    for (int i = t; i < EPB; i += 256) {
        int e = e0 + i;
        if (e < N_EDGESC) {
            int d = dst[e];
            int b = d >> 8;
            int pos = atomicAdd(&cur[b], 1);
            ebpack[pos] = (unsigned)src[e] | ((unsigned)(d & 255) << 16);
        }
    }
}

__global__ __launch_bounds__(256) void k_bbuild(const unsigned* __restrict__ ebpack,
        const int* __restrict__ boffB, int* __restrict__ offs,
        unsigned short* __restrict__ esrc) {
    __shared__ int deg[256];
    __shared__ int lofs[256];
    __shared__ unsigned short img[12288];
    int b = blockIdx.x;
    int t = threadIdx.x;
    int bbase = boffB[b];
    int cnt = boffB[b + 1] - bbase;
    deg[t] = 0;
    __syncthreads();
    for (int i = t; i < cnt; i += 256)
        atomicAdd(&deg[ebpack[bbase + i] >> 16], 1);
    __syncthreads();
    int v = deg[t];
    lofs[t] = v;
    __syncthreads();
    for (int d = 1; d < 256; d <<= 1) {
        int u = (t >= d) ? lofs[t - d] : 0;
        __syncthreads();
        lofs[t] += u;
        __syncthreads();
    }
    int excl = lofs[t] - v;
    int node = b * 256 + t;
    if (node < N_NODESC) offs[node] = bbase + excl;
    if (b == NBUCK - 1 && t == 0) offs[N_NODESC] = N_EDGESC;
    deg[t] = excl;
    __syncthreads();
    for (int i = t; i < cnt; i += 256) {
        unsigned p = ebpack[bbase + i];
        int pos = atomicAdd(&deg[p >> 16], 1);
        img[pos] = (unsigned short)(p & 0xFFFF);
    }
    __syncthreads();
    for (int i = t; i < cnt; i += 256)
        esrc[bbase + i] = img[i];
}

// ---------------- weight convert + swizzle to MFMA B-fragment order ----------------
__global__ __launch_bounds__(256) void k_wconv(const float* __restrict__ Wemb,
        const float* __restrict__ Ws, unsigned short* __restrict__ wsw) {
    int idx = blockIdx.x * 256 + threadIdx.x;
    const int EMB = IN_DIMC * HIDC;           // 32768
    const int LYR = 2 * HIDC * HIDC;          // 131072
    if (idx >= EMB + N_LAYERSC * LYR) return;
    float val; int k, n; unsigned short* basep;
    if (idx < EMB) {
        k = idx >> 8; n = idx & 255;
        val = Wemb[idx];
        basep = wsw;
    } else {
        int r = idx - EMB;
        int l = r >> 17;
        int r2 = r & (LYR - 1);
        k = r2 >> 8; n = r2 & 255;
        val = Ws[r];
        basep = wsw + EMB + l * LYR;
    }
    int off = (((k >> 5) * 16 + (n >> 4)) * 64 + ((((k >> 3) & 3) << 4) | (n & 15))) * 8 + (k & 7);
    basep[off] = f2b(val);
}

// ---------------- FUSED layer: gather-aggregate + 2-phase LDS GEMM + epilogue ----------------
// Block = 64 rows. panelA <- xb rows (async global_load_lds, swizzled);
// panelC <- fp8 gather mean of own rows (registers -> ds_write, swizzled).
// Then 16 K-steps (8 per panel) with 2-deep B pipeline. Epilogue: bias, row L2-norm,
// relu, residual -> xb (in-place, own rows) + xq_out (ping-pong vs xq_in).
__global__ __launch_bounds__(256, 2) void k_flayer(unsigned short* __restrict__ xb,
        const unsigned char* __restrict__ xqin, unsigned char* __restrict__ xqout,
        const int* __restrict__ offs, const unsigned short* __restrict__ esrc,
        const unsigned short* __restrict__ wb, const float* __restrict__ bias) {
    __shared__ unsigned short panelA[16384];  // 32 KB
    __shared__ unsigned short panelC[16384];  // 32 KB
    __shared__ float rs[64];
    int tid = threadIdx.x;
    int w = tid >> 6;
    int lane = tid & 63;
    int quad = lane >> 4;
    int l15 = lane & 15;
    int row0 = blockIdx.x * 64;

    // ---- issue phase-0 staging: xb own rows -> panelA (async) ----
    {
        int sboff = w * 8192 + lane * 16;
        #pragma unroll
        for (int i = 0; i < 8; i++) {
            int ldsoff = sboff + i * 1024;
            int r = ldsoff >> 9;
            int ch = (ldsoff & 511) >> 4;
            int lc = ch ^ (r & 15);
            const unsigned short* g = (const unsigned short*)xb + (size_t)(row0 + r) * HIDC + lc * 8;
            ldscp16(g, &panelA[w * 4096 + i * 512]);
        }
    }

    // ---- gather-aggregate own rows -> panelC ----
    {
        int gi = tid >> 4;       // 16 groups
        int li = tid & 15;       // lane covers cols li*16..+15
        #pragma unroll
        for (int it = 0; it < 4; it++) {
            int r = gi * 4 + it;             // 0..63
            int node = row0 + r;
            float a[16];
            #pragma unroll
            for (int j = 0; j < 16; j++) a[j] = 0.f;
            float wdeg = 1.f;
            if (node < N_NODESC) {
                int beg = offs[node], end = offs[node + 1];
                size_t loff = (size_t)li * 16;
                int e = beg;
                #define ACC16(v) do { \
                    floatx2 t0 = __builtin_amdgcn_cvt_pk_f32_fp8((v).x, false); \
                    floatx2 t1 = __builtin_amdgcn_cvt_pk_f32_fp8((v).x, true);  \
                    floatx2 t2 = __builtin_amdgcn_cvt_pk_f32_fp8((v).y, false); \
                    floatx2 t3 = __builtin_amdgcn_cvt_pk_f32_fp8((v).y, true);  \
                    floatx2 t4 = __builtin_amdgcn_cvt_pk_f32_fp8((v).z, false); \
                    floatx2 t5 = __builtin_amdgcn_cvt_pk_f32_fp8((v).z, true);  \
                    floatx2 t6 = __builtin_amdgcn_cvt_pk_f32_fp8((v).w, false); \
                    floatx2 t7 = __builtin_amdgcn_cvt_pk_f32_fp8((v).w, true);  \
                    a[0] += t0.x; a[1] += t0.y; a[2] += t1.x; a[3] += t1.y;     \
                    a[4] += t2.x; a[5] += t2.y; a[6] += t3.x; a[7] += t3.y;     \
                    a[8] += t4.x; a[9] += t4.y; a[10] += t5.x; a[11] += t5.y;   \
                    a[12] += t6.x; a[13] += t6.y; a[14] += t7.x; a[15] += t7.y; \
                } while (0)
                for (; e + 8 <= end; e += 8) {
                    int sidx[8];
                    #pragma unroll
                    for (int j = 0; j < 8; j++) sidx[j] = esrc[e + j];
                    uint4 v[8];
                    #pragma unroll
                    for (int j = 0; j < 8; j++)
                        v[j] = *(const uint4*)(xqin + (size_t)sidx[j] * HIDC + loff);
                    #pragma unroll
                    for (int j = 0; j < 8; j++) ACC16(v[j]);
                }
                if (e + 4 <= end) {
                    int sidx[4];
                    #pragma unroll
                    for (int j = 0; j < 4; j++) sidx[j] = esrc[e + j];
                    uint4 v[4];
                    #pragma unroll
                    for (int j = 0; j < 4; j++)
                        v[j] = *(const uint4*)(xqin + (size_t)sidx[j] * HIDC + loff);
                    #pragma unroll
                    for (int j = 0; j < 4; j++) ACC16(v[j]);
                    e += 4;
                }
                for (; e < end; e++) {
                    uint4 v = *(const uint4*)(xqin + (size_t)esrc[e] * HIDC + loff);
                    ACC16(v);
                }
                #undef ACC16
                wdeg = 1.0f / (float)max(end - beg, 1);
            }
            uint4 o0, o1;
            o0.x = pkb(a[0] * wdeg, a[1] * wdeg);
            o0.y = pkb(a[2] * wdeg, a[3] * wdeg);
            o0.z = pkb(a[4] * wdeg, a[5] * wdeg);
            o0.w = pkb(a[6] * wdeg, a[7] * wdeg);
            o1.x = pkb(a[8] * wdeg, a[9] * wdeg);
            o1.y = pkb(a[10] * wdeg, a[11] * wdeg);
            o1.z = pkb(a[12] * wdeg, a[13] * wdeg);
            o1.w = pkb(a[14] * wdeg, a[15] * wdeg);
            int phys0 = (2 * li) ^ (r & 15);
            int phys1 = (2 * li + 1) ^ (r & 15);
            *(uint4*)&panelC[r * 256 + phys0 * 8] = o0;
            *(uint4*)&panelC[r * 256 + phys1 * 8] = o1;
        }
    }
    __syncthreads();   // panelA (vmcnt drained) + panelC (lgkm) both ready

    // ---- 16 K-steps, 2-deep B pipeline ----
    floatx4 acc[4][4];
    #pragma unroll
    for (int mt = 0; mt < 4; mt++)
        #pragma unroll
        for (int n = 0; n < 4; n++)
            acc[mt][n] = (floatx4){0.f, 0.f, 0.f, 0.f};

    const unsigned short* bp = wb + ((size_t)(w * 4) * 64 + lane) * 8;  // step stride 8192
    short8 Bb[2][4];
    #define LOADB(slot, step) do { \
        const unsigned short* wp_ = bp + (size_t)(step) * 8192; \
        Bb[slot][0] = *(const short8*)(wp_); \
        Bb[slot][1] = *(const short8*)(wp_ + 512); \
        Bb[slot][2] = *(const short8*)(wp_ + 1024); \
        Bb[slot][3] = *(const short8*)(wp_ + 1536); \
    } while (0)
    LOADB(0, 0);
    #pragma unroll
    for (int st = 0; st < 16; st++) {
        const unsigned short* pan = (st < 8) ? panelA : panelC;
        int ks = st & 7;
        if (st + 1 < 16) LOADB((st + 1) & 1, st + 1);
        short8 afr[4];
        #pragma unroll
        for (int mt = 0; mt < 4; mt++) {
            int row = mt * 16 + l15;
            int phys = ((ks << 2) | quad) ^ l15;
            afr[mt] = *(const short8*)&pan[row * 256 + phys * 8];
        }
        #pragma unroll
        for (int mt = 0; mt < 4; mt++)
            #pragma unroll
            for (int n = 0; n < 4; n++)
                acc[mt][n] = __builtin_amdgcn_mfma_f32_16x16x32_bf16(
                    afr[mt], Bb[st & 1][n], acc[mt][n], 0, 0, 0);
    }
    #undef LOADB

    // ---- epilogue ----
    float bv[4];
    #pragma unroll
    for (int n = 0; n < 4; n++) bv[n] = bias[w * 64 + n * 16 + l15];
    #pragma unroll
    for (int mt = 0; mt < 4; mt++)
        #pragma unroll
        for (int n = 0; n < 4; n++)
            #pragma unroll
            for (int r = 0; r < 4; r++)
                acc[mt][n][r] += bv[n];

    __syncthreads();
    if (tid < 64) rs[tid] = 0.f;
    __syncthreads();
    #pragma unroll
    for (int mt = 0; mt < 4; mt++) {
        #pragma unroll
        for (int r = 0; r < 4; r++) {
            float p = acc[mt][0][r] * acc[mt][0][r] + acc[mt][1][r] * acc[mt][1][r]
                    + acc[mt][2][r] * acc[mt][2][r] + acc[mt][3][r] * acc[mt][3][r];
            p += __shfl_xor(p, 1);
            p += __shfl_xor(p, 2);
            p += __shfl_xor(p, 4);
            p += __shfl_xor(p, 8);
            if (l15 == 0) atomicAdd(&rs[mt * 16 + quad * 4 + r], p);
        }
    }
    __syncthreads();

    #pragma unroll
    for (int mt = 0; mt < 4; mt++) {
        #pragma unroll
        for (int r = 0; r < 4; r++) {
            int row = row0 + mt * 16 + quad * 4 + r;
            if (row < N_NODESC) {
                float inv = 1.0f / fmaxf(sqrtf(rs[mt * 16 + quad * 4 + r]), EPSV);
                #pragma unroll
                for (int n = 0; n < 4; n++) {
                    int col = w * 64 + n * 16 + l15;
                    size_t idx = (size_t)row * HIDC + col;
                    float xo = b2f(xb[idx]);
                    float v = fmaxf(acc[mt][n][r] * inv, 0.f);
                    float nv = xo + v;
                    xb[idx] = f2b(nv);
                    xqout[idx] = f2q(nv);
                }
            }
        }
    }
}

// ---------------- embed GEMM: 32-row blocks, direct fp32 frag loads ----------------
__global__ __launch_bounds__(256, 4) void k_egemm(const float* __restrict__ h,
        const unsigned short* __restrict__ wsw, const float* __restrict__ bias,
        unsigned short* __restrict__ xb, unsigned char* __restrict__ xq) {
    int tid = threadIdx.x;
    int wn = tid >> 6;
    int lane = tid & 63;
    int quad = lane >> 4;
    int l15 = lane & 15;
    int row0 = blockIdx.x * 32;

    floatx4 acc[2][4];
    #pragma unroll
    for (int mt = 0; mt < 2; mt++)
        #pragma unroll
        for (int n = 0; n < 4; n++)
            acc[mt][n] = (floatx4){0.f, 0.f, 0.f, 0.f};

    int r0 = row0 + l15;
    int r1 = row0 + 16 + l15;
    bool ok0 = r0 < N_NODESC, ok1 = r1 < N_NODESC;
    const float* h0 = h + (size_t)r0 * IN_DIMC + quad * 8;
    const float* h1 = h + (size_t)r1 * IN_DIMC + quad * 8;
    const unsigned short* bp = wsw + ((size_t)(wn * 4) * 64 + lane) * 8;

    #pragma unroll
    for (int ks = 0; ks < 4; ks++) {
        float4 f00 = ok0 ? *(const float4*)(h0 + ks * 32)     : (float4){0,0,0,0};
        float4 f01 = ok0 ? *(const float4*)(h0 + ks * 32 + 4) : (float4){0,0,0,0};
        float4 f10 = ok1 ? *(const float4*)(h1 + ks * 32)     : (float4){0,0,0,0};
        float4 f11 = ok1 ? *(const float4*)(h1 + ks * 32 + 4) : (float4){0,0,0,0};
        short8 afr[2], bfr[4];
        uint4 av;
        av.x = pkb(f00.x, f00.y); av.y = pkb(f00.z, f00.w);
        av.z = pkb(f01.x, f01.y); av.w = pkb(f01.z, f01.w);
        afr[0] = *(short8*)&av;
        av.x = pkb(f10.x, f10.y); av.y = pkb(f10.z, f10.w);
        av.z = pkb(f11.x, f11.y); av.w = pkb(f11.z, f11.w);
        afr[1] = *(short8*)&av;
        const unsigned short* wp = bp + (size_t)ks * 8192;
        #pragma unroll
        for (int n = 0; n < 4; n++)
            bfr[n] = *(const short8*)(wp + n * 512);
        #pragma unroll
        for (int mt = 0; mt < 2; mt++)
            #pragma unroll
            for (int n = 0; n < 4; n++)
                acc[mt][n] = __builtin_amdgcn_mfma_f32_16x16x32_bf16(
                    afr[mt], bfr[n], acc[mt][n], 0, 0, 0);
    }

    float bv[4];
    #pragma unroll
    for (int n = 0; n < 4; n++) bv[n] = bias[wn * 64 + n * 16 + l15];
    #pragma unroll
    for (int mt = 0; mt < 2; mt++) {
        #pragma unroll
        for (int r = 0; r < 4; r++) {
            int row = row0 + mt * 16 + quad * 4 + r;
            if (row < N_NODESC) {
                #pragma unroll
                for (int n = 0; n < 4; n++) {
                    int col = wn * 64 + n * 16 + l15;
                    float v = acc[mt][n][r] + bv[n];
                    size_t idx = (size_t)row * HIDC + col;
                    xb[idx] = f2b(v);
                    xq[idx] = f2q(v);
                }
            }
        }
    }
}

// ---------------- graph mean-pool: 1 block per (graph, 64-col quarter) ----------------
__global__ __launch_bounds__(256) void k_pool(const unsigned short* __restrict__ xb,
        const int* __restrict__ gstart, float* __restrict__ hg) {
    __shared__ float red[256][8];
    int g = blockIdx.x >> 2;
    int cq = blockIdx.x & 3;
    int t = threadIdx.x;
    int cchunk = t & 7;
    int rgrp = t >> 3;
    int col0 = cq * 64 + cchunk * 8;
    int beg = gstart[g], end = gstart[g + 1];
    float a[8];
    #pragma unroll
    for (int j = 0; j < 8; j++) a[j] = 0.f;
    for (int r = beg + rgrp; r < end; r += 32) {
        uint4 v = *(const uint4*)(xb + (size_t)r * HIDC + col0);
        a[0] += blo(v.x); a[1] += bhi(v.x);
        a[2] += blo(v.y); a[3] += bhi(v.y);
        a[4] += blo(v.z); a[5] += bhi(v.z);
        a[6] += blo(v.w); a[7] += bhi(v.w);
    }
    #pragma unroll
    for (int j = 0; j < 8; j++) red[t][j] = a[j];
    __syncthreads();
    for (int d = 16; d >= 1; d >>= 1) {
        if (rgrp < d) {
            #pragma unroll
            for (int j = 0; j < 8; j++) red[t][j] += red[t + d * 8][j];
        }
        __syncthreads();
    }
    if (rgrp == 0) {
        float inv = 1.0f / (float)max(end - beg, 1);
        #pragma unroll
        for (int j = 0; j < 8; j++)
            hg[g * HIDC + col0 + j] = red[t][j] * inv;
    }
}

// ---------------- readout ----------------
__global__ __launch_bounds__(256) void k_readout(const float* __restrict__ hg,
        const float* __restrict__ ppos, const float* __restrict__ pneg,
        const float* __restrict__ wfc, float* __restrict__ out) {
    __shared__ float red[256];
    __shared__ float ss[10];
    int t = threadIdx.x;
    int g = blockIdx.x;
    float hgv = hg[g * HIDC + t];
    for (int p = 0; p < 10; p++) {
        const float* P = (p < 5) ? (ppos + p * HIDC) : (pneg + (p - 5) * HIDC);
        float d = hgv - P[t];
        red[t] = d * d;
        __syncthreads();
        for (int s2 = 128; s2 > 0; s2 >>= 1) {
            if (t < s2) red[t] += red[t + s2];
            __syncthreads();
        }
        if (t == 0) {
            float dd = red[0];
            ss[p] = logf((dd + 1.0f) / (dd + EPSV));
        }
        __syncthreads();
    }
    if (t == 0) {
        float y = 0.f;
        #pragma unroll
        for (int p = 0; p < 10; p++) y += ss[p] * wfc[p];
        out[g] = 1.0f / (1.0f + expf(-y));
    }
}

extern "C" void kernel_launch(void* const* d_in, const int* in_sizes, int n_in,
                              void* d_out, int out_size, void* d_ws, size_t ws_size,
                              hipStream_t stream) {
    const float* h    = (const float*)d_in[0];
    const int*   src  = (const int*)d_in[1];
    const int*   dst  = (const int*)d_in[2];
    const int*   gid  = (const int*)d_in[3];
    const float* Wemb = (const float*)d_in[4];
    const float* bemb = (const float*)d_in[5];
    const float* Ws   = (const float*)d_in[6];
    const float* bs   = (const float*)d_in[7];
    const float* ppos = (const float*)d_in[8];
    const float* pneg = (const float*)d_in[9];
    const float* wfc  = (const float*)d_in[10];
    float* out = (float*)d_out;

    char* ws = (char*)d_ws;
    size_t off = 0;
    auto alloc = [&](size_t bytes) {
        void* p = ws + off;
        off += (bytes + 255) & ~(size_t)255;
        return p;
    };
    unsigned short* xb     = (unsigned short*)alloc((size_t)NPAD * HIDC * 2);  // bf16 row-major
    unsigned char*  xq0    = (unsigned char*)alloc((size_t)NPAD * HIDC);       // fp8 ping
    unsigned char*  xq1    = (unsigned char*)alloc((size_t)NPAD * HIDC);       // fp8 pong
    unsigned short* wsw    = (unsigned short*)alloc((size_t)(IN_DIMC * HIDC + N_LAYERSC * 2 * HIDC * HIDC) * 2);
    int*            offs   = (int*)alloc((size_t)(N_NODESC + 1) * 4);
    unsigned short* esrc   = (unsigned short*)alloc((size_t)N_EDGESC * 2);
    unsigned*       ebpack = (unsigned*)alloc((size_t)N_EDGESC * 4);
    int*            gbcnt  = (int*)alloc((size_t)NBUCK * 4);
    int*            boffB  = (int*)alloc((size_t)(NBUCK + 1) * 4);
    int*            gcurB  = (int*)alloc((size_t)NBUCK * 4);
    int*            gstart = (int*)alloc((size_t)(N_GRAPHSC + 1) * 4);
    float*          hg     = (float*)alloc((size_t)N_GRAPHSC * HIDC * 4);
    (void)ws_size; (void)in_sizes; (void)n_in; (void)out_size;

    hipMemsetAsync(gbcnt, 0, (size_t)NBUCK * 4, stream);

    const int WTOT = IN_DIMC * HIDC + N_LAYERSC * 2 * HIDC * HIDC; // 557056
    k_wconv<<<(WTOT + 255) / 256, 256, 0, stream>>>(Wemb, Ws, wsw);
    k_gbounds<<<1, 128, 0, stream>>>(gid, gstart);
    k_bcount<<<NBLK1, 256, 0, stream>>>(dst, gbcnt);
    k_bscan<<<1, 256, 0, stream>>>(gbcnt, boffB, gcurB);
    k_bscatter<<<NBLK1, 256, 0, stream>>>(src, dst, gcurB, ebpack);
    k_bbuild<<<NBUCK, 256, 0, stream>>>(ebpack, boffB, offs, esrc);

    k_egemm<<<NPAD / 32, 256, 0, stream>>>(h, wsw, bemb, xb, xq0);

    unsigned char* xqs[2] = {xq0, xq1};
    for (int l = 0; l < N_LAYERSC; l++) {
        k_flayer<<<NPAD / 64, 256, 0, stream>>>(
            xb, xqs[l & 1], xqs[(l + 1) & 1], offs, esrc,
            wsw + IN_DIMC * HIDC + (size_t)l * 2 * HIDC * HIDC,
            bs + (size_t)l * HIDC);
    }
    k_pool<<<N_GRAPHSC * 4, 256, 0, stream>>>(xb, gstart, hg);
    k_readout<<<N_GRAPHSC, 256, 0, stream>>>(hg, ppos, pneg, wfc, out);
}

// Round 13
// 480.677 us; speedup vs baseline: 1.0952x; 1.0952x over previous
//
#include <hip/hip_runtime.h>
#include <math.h>

#define N_NODESC 50000
#define NPAD 50048              // 782 * 64
#define N_EDGESC 800000
#define N_GRAPHSC 64
#define IN_DIMC 128
#define HIDC 256
#define N_LAYERSC 4
#define EPSV 1e-12f

#define NBUCK 196               // buckets of 256 nodes
#define EPB 4096
#define NBLK1 196               // ceil(800000/4096)

typedef __attribute__((ext_vector_type(8))) short short8;
typedef __attribute__((ext_vector_type(4))) float floatx4;
typedef __attribute__((ext_vector_type(2))) float floatx2;

__device__ __forceinline__ unsigned short f2b(float f) {
    union { float f; unsigned u; } v; v.f = f;
    unsigned r = v.u + 0x7FFFu + ((v.u >> 16) & 1u);
    return (unsigned short)(r >> 16);
}
__device__ __forceinline__ float blo(unsigned u) { return __uint_as_float(u << 16); }
__device__ __forceinline__ float bhi(unsigned u) { return __uint_as_float(u & 0xFFFF0000u); }
__device__ __forceinline__ unsigned pkb(float a, float b) {
    return (unsigned)f2b(a) | ((unsigned)f2b(b) << 16);
}
__device__ __forceinline__ float b2f(unsigned short s) {
    return __uint_as_float((unsigned)s << 16);
}
__device__ __forceinline__ unsigned char f2q(float v) {
    return (unsigned char)(__builtin_amdgcn_cvt_pk_fp8_f32(v, v, 0, false) & 0xFF);
}
__device__ __forceinline__ void ldscp16(const void* g, void* l) {
    __builtin_amdgcn_global_load_lds(
        (const __attribute__((address_space(1))) unsigned int*)g,
        (__attribute__((address_space(3))) unsigned int*)l, 16, 0, 0);
}

// ---------------- graph boundaries via binary search (gid sorted) ----------------
__global__ __launch_bounds__(128) void k_gbounds(const int* __restrict__ gid,
        int* __restrict__ gstart) {
    int g = threadIdx.x;
    if (g > N_GRAPHSC) return;
    int lo = 0, hi = N_NODESC;
    while (lo < hi) {
        int mid = (lo + hi) >> 1;
        if (gid[mid] < g) lo = mid + 1; else hi = mid;
    }
    gstart[g] = lo;
}

// ---------------- CSR build, bucketed (bucket = dst>>8) ----------------
__global__ __launch_bounds__(256) void k_bcount(const int* __restrict__ dst,
        int* __restrict__ gbcnt) {
    __shared__ int bc[256];
    int t = threadIdx.x;
    bc[t] = 0;
    __syncthreads();
    int e0 = blockIdx.x * EPB;
    for (int i = t; i < EPB; i += 256) {
        int e = e0 + i;
        if (e < N_EDGESC) atomicAdd(&bc[dst[e] >> 8], 1);
    }
    __syncthreads();
    if (t < NBUCK && bc[t] > 0) atomicAdd(&gbcnt[t], bc[t]);
}

__global__ __launch_bounds__(256) void k_bscan(const int* __restrict__ gbcnt,
        int* __restrict__ boffB, int* __restrict__ gcurB) {
    __shared__ int s[256];
    int t = threadIdx.x;
    int v = (t < NBUCK) ? gbcnt[t] : 0;
    s[t] = v;
    __syncthreads();
    for (int d = 1; d < 256; d <<= 1) {
        int u = (t >= d) ? s[t - d] : 0;
        __syncthreads();
        s[t] += u;
        __syncthreads();
    }
    if (t < NBUCK) {
        int excl = s[t] - v;
        boffB[t] = excl;
        gcurB[t] = excl;
    }
    if (t == 0) boffB[NBUCK] = N_EDGESC;
}

__global__ __launch_bounds__(256) void k_bscatter(const int* __restrict__ src,
        const int* __restrict__ dst, int* __restrict__ gcurB,
        unsigned* __restrict__ ebpack) {
    __shared__ int bc[256];
    __shared__ int cur[256];
    int t = threadIdx.x;
    bc[t] = 0;
    __syncthreads();
    int e0 = blockIdx.x * EPB;
    for (int i = t; i < EPB; i += 256) {
        int e = e0 + i;
        if (e < N_EDGESC) atomicAdd(&bc[dst[e] >> 8], 1);
    }
    __syncthreads();
    if (t < NBUCK)
        cur[t] = (bc[t] > 0) ? atomicAdd(&gcurB[t], bc[t]) : 0;
    __syncthreads();
    for (int i = t; i < EPB; i += 256) {
        int e = e0 + i;
        if (e < N_EDGESC) {
            int d = dst[e];
            int b = d >> 8;
            int pos = atomicAdd(&cur[b], 1);
            ebpack[pos] = (unsigned)src[e] | ((unsigned)(d & 255) << 16);
        }
    }
}

__global__ __launch_bounds__(256) void k_bbuild(const unsigned* __restrict__ ebpack,
        const int* __restrict__ boffB, int* __restrict__ offs,
        unsigned short* __restrict__ esrc) {
    __shared__ int deg[256];
    __shared__ int lofs[256];
    __shared__ unsigned short img[12288];
    int b = blockIdx.x;
    int t = threadIdx.x;
    int bbase = boffB[b];
    int cnt = boffB[b + 1] - bbase;
    deg[t] = 0;
    __syncthreads();
    for (int i = t; i < cnt; i += 256)
        atomicAdd(&deg[ebpack[bbase + i] >> 16], 1);
    __syncthreads();
    int v = deg[t];
    lofs[t] = v;
    __syncthreads();
    for (int d = 1; d < 256; d <<= 1) {
        int u = (t >= d) ? lofs[t - d] : 0;
        __syncthreads();
        lofs[t] += u;
        __syncthreads();
    }
    int excl = lofs[t] - v;
    int node = b * 256 + t;
    if (node < N_NODESC) offs[node] = bbase + excl;
    if (b == NBUCK - 1 && t == 0) offs[N_NODESC] = N_EDGESC;
    deg[t] = excl;
    __syncthreads();
    for (int i = t; i < cnt; i += 256) {
        unsigned p = ebpack[bbase + i];
        int pos = atomicAdd(&deg[p >> 16], 1);
        img[pos] = (unsigned short)(p & 0xFFFF);
    }
    __syncthreads();
    for (int i = t; i < cnt; i += 256)
        esrc[bbase + i] = img[i];
}

// ---------------- weight convert + swizzle to MFMA B-fragment order ----------------
__global__ __launch_bounds__(256) void k_wconv(const float* __restrict__ Wemb,
        const float* __restrict__ Ws, unsigned short* __restrict__ wsw) {
    int idx = blockIdx.x * 256 + threadIdx.x;
    const int EMB = IN_DIMC * HIDC;           // 32768
    const int LYR = 2 * HIDC * HIDC;          // 131072
    if (idx >= EMB + N_LAYERSC * LYR) return;
    float val; int k, n; unsigned short* basep;
    if (idx < EMB) {
        k = idx >> 8; n = idx & 255;
        val = Wemb[idx];
        basep = wsw;
    } else {
        int r = idx - EMB;
        int l = r >> 17;
        int r2 = r & (LYR - 1);
        k = r2 >> 8; n = r2 & 255;
        val = Ws[r];
        basep = wsw + EMB + l * LYR;
    }
    int off = (((k >> 5) * 16 + (n >> 4)) * 64 + ((((k >> 3) & 3) << 4) | (n & 15))) * 8 + (k & 7);
    basep[off] = f2b(val);
}

// ---------------- per-node mean aggregation: fp8 gather (16 lanes/node, uint4) ----------------
__global__ __launch_bounds__(256) void k_aggregate(const unsigned char* __restrict__ xq,
        const int* __restrict__ offs, const unsigned short* __restrict__ esrc,
        unsigned short* __restrict__ cb) {
    int gidx = blockIdx.x * 256 + threadIdx.x;
    int node = gidx >> 4;
    int lane = threadIdx.x & 15;          // covers fp8 cols [lane*16, lane*16+16)
    if (node >= N_NODESC) return;
    int beg = offs[node], end = offs[node + 1];
    float a[16];
    #pragma unroll
    for (int j = 0; j < 16; j++) a[j] = 0.f;
    size_t loff = (size_t)lane * 16;
    int e = beg;
    #define ACC16(v) do { \
        floatx2 t0 = __builtin_amdgcn_cvt_pk_f32_fp8((v).x, false); \
        floatx2 t1 = __builtin_amdgcn_cvt_pk_f32_fp8((v).x, true);  \
        floatx2 t2 = __builtin_amdgcn_cvt_pk_f32_fp8((v).y, false); \
        floatx2 t3 = __builtin_amdgcn_cvt_pk_f32_fp8((v).y, true);  \
        floatx2 t4 = __builtin_amdgcn_cvt_pk_f32_fp8((v).z, false); \
        floatx2 t5 = __builtin_amdgcn_cvt_pk_f32_fp8((v).z, true);  \
        floatx2 t6 = __builtin_amdgcn_cvt_pk_f32_fp8((v).w, false); \
        floatx2 t7 = __builtin_amdgcn_cvt_pk_f32_fp8((v).w, true);  \
        a[0] += t0.x; a[1] += t0.y; a[2] += t1.x; a[3] += t1.y;     \
        a[4] += t2.x; a[5] += t2.y; a[6] += t3.x; a[7] += t3.y;     \
        a[8] += t4.x; a[9] += t4.y; a[10] += t5.x; a[11] += t5.y;   \
        a[12] += t6.x; a[13] += t6.y; a[14] += t7.x; a[15] += t7.y; \
    } while (0)
    for (; e + 8 <= end; e += 8) {
        int sidx[8];
        #pragma unroll
        for (int j = 0; j < 8; j++) sidx[j] = esrc[e + j];
        uint4 v[8];
        #pragma unroll
        for (int j = 0; j < 8; j++)
            v[j] = *(const uint4*)(xq + (size_t)sidx[j] * HIDC + loff);
        #pragma unroll
        for (int j = 0; j < 8; j++) ACC16(v[j]);
    }
    if (e + 4 <= end) {
        int sidx[4];
        #pragma unroll
        for (int j = 0; j < 4; j++) sidx[j] = esrc[e + j];
        uint4 v[4];
        #pragma unroll
        for (int j = 0; j < 4; j++)
            v[j] = *(const uint4*)(xq + (size_t)sidx[j] * HIDC + loff);
        #pragma unroll
        for (int j = 0; j < 4; j++) ACC16(v[j]);
        e += 4;
    }
    for (; e < end; e++) {
        uint4 v = *(const uint4*)(xq + (size_t)esrc[e] * HIDC + loff);
        ACC16(v);
    }
    #undef ACC16
    float w = 1.0f / (float)max(end - beg, 1);
    uint4 o0, o1;
    o0.x = pkb(a[0] * w, a[1] * w);
    o0.y = pkb(a[2] * w, a[3] * w);
    o0.z = pkb(a[4] * w, a[5] * w);
    o0.w = pkb(a[6] * w, a[7] * w);
    o1.x = pkb(a[8] * w, a[9] * w);
    o1.y = pkb(a[10] * w, a[11] * w);
    o1.z = pkb(a[12] * w, a[13] * w);
    o1.w = pkb(a[14] * w, a[15] * w);
    unsigned short* cp = cb + (size_t)node * HIDC + lane * 16;
    *(uint4*)cp = o0;
    *(uint4*)(cp + 8) = o1;
}

// ---------------- layer GEMM: A-panel in LDS via global_load_lds, 64-row blocks ----------------
__global__ __launch_bounds__(256, 4) void k_lgemm(unsigned short* __restrict__ xb,
        const unsigned short* __restrict__ cbr, const unsigned short* __restrict__ wb,
        const float* __restrict__ bias, unsigned char* __restrict__ xq) {
    __shared__ unsigned short As[16384];   // 32 KB panel
    __shared__ float rs[64];
    int tid = threadIdx.x;
    int w = tid >> 6;
    int lane = tid & 63;
    int quad = lane >> 4;
    int l15 = lane & 15;
    int row0 = blockIdx.x * 64;

    floatx4 acc[4][4];
    #pragma unroll
    for (int mt = 0; mt < 4; mt++)
        #pragma unroll
        for (int n = 0; n < 4; n++)
            acc[mt][n] = (floatx4){0.f, 0.f, 0.f, 0.f};

    const unsigned short* bp = wb + ((size_t)(w * 4) * 64 + lane) * 8;  // step stride 8192

    int sboff = (tid >> 6) * 8192 + lane * 16;
    #pragma unroll
    for (int phase = 0; phase < 2; phase++) {
        const unsigned short* srcb = (phase == 0) ? (const unsigned short*)xb : cbr;
        if (phase == 1) __syncthreads();
        #pragma unroll
        for (int i = 0; i < 8; i++) {
            int ldsoff = sboff + i * 1024;
            int r = ldsoff >> 9;
            int ch = (ldsoff & 511) >> 4;
            int lc = ch ^ (r & 15);
            const unsigned short* g = srcb + (size_t)(row0 + r) * HIDC + lc * 8;
            ldscp16(g, &As[w * 4096 + i * 512]);
        }
        __syncthreads();

        #pragma unroll
        for (int ks = 0; ks < 8; ks++) {
            short8 afr[4], bfr[4];
            #pragma unroll
            for (int mt = 0; mt < 4; mt++) {
                int row = mt * 16 + l15;
                int phys = ((ks << 2) | quad) ^ l15;
                afr[mt] = *(const short8*)&As[row * 256 + phys * 8];
            }
            const unsigned short* wp = bp + (size_t)(phase * 8 + ks) * 8192;
            #pragma unroll
            for (int n = 0; n < 4; n++)
                bfr[n] = *(const short8*)(wp + n * 512);
            #pragma unroll
            for (int mt = 0; mt < 4; mt++)
                #pragma unroll
                for (int n = 0; n < 4; n++)
                    acc[mt][n] = __builtin_amdgcn_mfma_f32_16x16x32_bf16(
                        afr[mt], bfr[n], acc[mt][n], 0, 0, 0);
        }
    }

    float bv[4];
    #pragma unroll
    for (int n = 0; n < 4; n++) bv[n] = bias[w * 64 + n * 16 + l15];
    #pragma unroll
    for (int mt = 0; mt < 4; mt++)
        #pragma unroll
        for (int n = 0; n < 4; n++)
            #pragma unroll
            for (int r = 0; r < 4; r++)
                acc[mt][n][r] += bv[n];

    __syncthreads();
    if (tid < 64) rs[tid] = 0.f;
    __syncthreads();
    #pragma unroll
    for (int mt = 0; mt < 4; mt++) {
        #pragma unroll
        for (int r = 0; r < 4; r++) {
            float p = acc[mt][0][r] * acc[mt][0][r] + acc[mt][1][r] * acc[mt][1][r]
                    + acc[mt][2][r] * acc[mt][2][r] + acc[mt][3][r] * acc[mt][3][r];
            p += __shfl_xor(p, 1);
            p += __shfl_xor(p, 2);
            p += __shfl_xor(p, 4);
            p += __shfl_xor(p, 8);
            if (l15 == 0) atomicAdd(&rs[mt * 16 + quad * 4 + r], p);
        }
    }
    __syncthreads();

    #pragma unroll
    for (int mt = 0; mt < 4; mt++) {
        #pragma unroll
        for (int r = 0; r < 4; r++) {
            int row = row0 + mt * 16 + quad * 4 + r;
            if (row < N_NODESC) {
                float inv = 1.0f / fmaxf(sqrtf(rs[mt * 16 + quad * 4 + r]), EPSV);
                #pragma unroll
                for (int n = 0; n < 4; n++) {
                    int col = w * 64 + n * 16 + l15;
                    size_t idx = (size_t)row * HIDC + col;
                    float xo = b2f(xb[idx]);
                    float v = fmaxf(acc[mt][n][r] * inv, 0.f);
                    float nv = xo + v;
                    xb[idx] = f2b(nv);
                    xq[idx] = f2q(nv);
                }
            }
        }
    }
}

// ---------------- embed GEMM: 32-row blocks, direct fp32 frag loads ----------------
__global__ __launch_bounds__(256, 4) void k_egemm(const float* __restrict__ h,
        const unsigned short* __restrict__ wsw, const float* __restrict__ bias,
        unsigned short* __restrict__ xb, unsigned char* __restrict__ xq) {
    int tid = threadIdx.x;
    int wn = tid >> 6;
    int lane = tid & 63;
    int quad = lane >> 4;
    int l15 = lane & 15;
    int row0 = blockIdx.x * 32;

    floatx4 acc[2][4];
    #pragma unroll
    for (int mt = 0; mt < 2; mt++)
        #pragma unroll
        for (int n = 0; n < 4; n++)
            acc[mt][n] = (floatx4){0.f, 0.f, 0.f, 0.f};

    int r0 = row0 + l15;
    int r1 = row0 + 16 + l15;
    bool ok0 = r0 < N_NODESC, ok1 = r1 < N_NODESC;
    const float* h0 = h + (size_t)r0 * IN_DIMC + quad * 8;
    const float* h1 = h + (size_t)r1 * IN_DIMC + quad * 8;
    const unsigned short* bp = wsw + ((size_t)(wn * 4) * 64 + lane) * 8;

    #pragma unroll
    for (int ks = 0; ks < 4; ks++) {
        float4 f00 = ok0 ? *(const float4*)(h0 + ks * 32)     : (float4){0,0,0,0};
        float4 f01 = ok0 ? *(const float4*)(h0 + ks * 32 + 4) : (float4){0,0,0,0};
        float4 f10 = ok1 ? *(const float4*)(h1 + ks * 32)     : (float4){0,0,0,0};
        float4 f11 = ok1 ? *(const float4*)(h1 + ks * 32 + 4) : (float4){0,0,0,0};
        short8 afr[2], bfr[4];
        uint4 av;
        av.x = pkb(f00.x, f00.y); av.y = pkb(f00.z, f00.w);
        av.z = pkb(f01.x, f01.y); av.w = pkb(f01.z, f01.w);
        afr[0] = *(short8*)&av;
        av.x = pkb(f10.x, f10.y); av.y = pkb(f10.z, f10.w);
        av.z = pkb(f11.x, f11.y); av.w = pkb(f11.z, f11.w);
        afr[1] = *(short8*)&av;
        const unsigned short* wp = bp + (size_t)ks * 8192;
        #pragma unroll
        for (int n = 0; n < 4; n++)
            bfr[n] = *(const short8*)(wp + n * 512);
        #pragma unroll
        for (int mt = 0; mt < 2; mt++)
            #pragma unroll
            for (int n = 0; n < 4; n++)
                acc[mt][n] = __builtin_amdgcn_mfma_f32_16x16x32_bf16(
                    afr[mt], bfr[n], acc[mt][n], 0, 0, 0);
    }

    float bv[4];
    #pragma unroll
    for (int n = 0; n < 4; n++) bv[n] = bias[wn * 64 + n * 16 + l15];
    #pragma unroll
    for (int mt = 0; mt < 2; mt++) {
        #pragma unroll
        for (int r = 0; r < 4; r++) {
            int row = row0 + mt * 16 + quad * 4 + r;
            if (row < N_NODESC) {
                #pragma unroll
                for (int n = 0; n < 4; n++) {
                    int col = wn * 64 + n * 16 + l15;
                    float v = acc[mt][n][r] + bv[n];
                    size_t idx = (size_t)row * HIDC + col;
                    xb[idx] = f2b(v);
                    xq[idx] = f2q(v);
                }
            }
        }
    }
}

// ---------------- graph mean-pool: 1 block per (graph, 64-col quarter) ----------------
__global__ __launch_bounds__(256) void k_pool(const unsigned short* __restrict__ xb,
        const int* __restrict__ gstart, float* __restrict__ hg) {
    __shared__ float red[256][8];
    int g = blockIdx.x >> 2;
    int cq = blockIdx.x & 3;
    int t = threadIdx.x;
    int cchunk = t & 7;
    int rgrp = t >> 3;
    int col0 = cq * 64 + cchunk * 8;
    int beg = gstart[g], end = gstart[g + 1];
    float a[8];
    #pragma unroll
    for (int j = 0; j < 8; j++) a[j] = 0.f;
    for (int r = beg + rgrp; r < end; r += 32) {
        uint4 v = *(const uint4*)(xb + (size_t)r * HIDC + col0);
        a[0] += blo(v.x); a[1] += bhi(v.x);
        a[2] += blo(v.y); a[3] += bhi(v.y);
        a[4] += blo(v.z); a[5] += bhi(v.z);
        a[6] += blo(v.w); a[7] += bhi(v.w);
    }
    #pragma unroll
    for (int j = 0; j < 8; j++) red[t][j] = a[j];
    __syncthreads();
    for (int d = 16; d >= 1; d >>= 1) {
        if (rgrp < d) {
            #pragma unroll
            for (int j = 0; j < 8; j++) red[t][j] += red[t + d * 8][j];
        }
        __syncthreads();
    }
    if (rgrp == 0) {
        float inv = 1.0f / (float)max(end - beg, 1);
        #pragma unroll
        for (int j = 0; j < 8; j++)
            hg[g * HIDC + col0 + j] = red[t][j] * inv;
    }
}

// ---------------- readout ----------------
__global__ __launch_bounds__(256) void k_readout(const float* __restrict__ hg,
        const float* __restrict__ ppos, const float* __restrict__ pneg,
        const float* __restrict__ wfc, float* __restrict__ out) {
    __shared__ float red[256];
    __shared__ float ss[10];
    int t = threadIdx.x;
    int g = blockIdx.x;
    float hgv = hg[g * HIDC + t];
    for (int p = 0; p < 10; p++) {
        const float* P = (p < 5) ? (ppos + p * HIDC) : (pneg + (p - 5) * HIDC);
        float d = hgv - P[t];
        red[t] = d * d;
        __syncthreads();
        for (int s2 = 128; s2 > 0; s2 >>= 1) {
            if (t < s2) red[t] += red[t + s2];
            __syncthreads();
        }
        if (t == 0) {
            float dd = red[0];
            ss[p] = logf((dd + 1.0f) / (dd + EPSV));
        }
        __syncthreads();
    }
    if (t == 0) {
        float y = 0.f;
        #pragma unroll
        for (int p = 0; p < 10; p++) y += ss[p] * wfc[p];
        out[g] = 1.0f / (1.0f + expf(-y));
    }
}

extern "C" void kernel_launch(void* const* d_in, const int* in_sizes, int n_in,
                              void* d_out, int out_size, void* d_ws, size_t ws_size,
                              hipStream_t stream) {
    const float* h    = (const float*)d_in[0];
    const int*   src  = (const int*)d_in[1];
    const int*   dst  = (const int*)d_in[2];
    const int*   gid  = (const int*)d_in[3];
    const float* Wemb = (const float*)d_in[4];
    const float* bemb = (const float*)d_in[5];
    const float* Ws   = (const float*)d_in[6];
    const float* bs   = (const float*)d_in[7];
    const float* ppos = (const float*)d_in[8];
    const float* pneg = (const float*)d_in[9];
    const float* wfc  = (const float*)d_in[10];
    float* out = (float*)d_out;

    char* ws = (char*)d_ws;
    size_t off = 0;
    auto alloc = [&](size_t bytes) {
        void* p = ws + off;
        off += (bytes + 255) & ~(size_t)255;
        return p;
    };
    unsigned short* xb     = (unsigned short*)alloc((size_t)NPAD * HIDC * 2);  // bf16 row-major
    unsigned char*  xq     = (unsigned char*)alloc((size_t)NPAD * HIDC);       // fp8 shadow
    unsigned short* cb     = (unsigned short*)alloc((size_t)NPAD * HIDC * 2);  // bf16 row-major
    unsigned short* wsw    = (unsigned short*)alloc((size_t)(IN_DIMC * HIDC + N_LAYERSC * 2 * HIDC * HIDC) * 2);
    int*            offs   = (int*)alloc((size_t)(N_NODESC + 1) * 4);
    unsigned short* esrc   = (unsigned short*)alloc((size_t)N_EDGESC * 2);
    unsigned*       ebpack = (unsigned*)alloc((size_t)N_EDGESC * 4);
    int*            gbcnt  = (int*)alloc((size_t)NBUCK * 4);
    int*            boffB  = (int*)alloc((size_t)(NBUCK + 1) * 4);
    int*            gcurB  = (int*)alloc((size_t)NBUCK * 4);
    int*            gstart = (int*)alloc((size_t)(N_GRAPHSC + 1) * 4);
    float*          hg     = (float*)alloc((size_t)N_GRAPHSC * HIDC * 4);
    (void)ws_size; (void)in_sizes; (void)n_in; (void)out_size;

    hipMemsetAsync(gbcnt, 0, (size_t)NBUCK * 4, stream);

    const int WTOT = IN_DIMC * HIDC + N_LAYERSC * 2 * HIDC * HIDC; // 557056
    k_wconv<<<(WTOT + 255) / 256, 256, 0, stream>>>(Wemb, Ws, wsw);
    k_gbounds<<<1, 128, 0, stream>>>(gid, gstart);
    k_bcount<<<NBLK1, 256, 0, stream>>>(dst, gbcnt);
    k_bscan<<<1, 256, 0, stream>>>(gbcnt, boffB, gcurB);
    k_bscatter<<<NBLK1, 256, 0, stream>>>(src, dst, gcurB, ebpack);
    k_bbuild<<<NBUCK, 256, 0, stream>>>(ebpack, boffB, offs, esrc);

    k_egemm<<<NPAD / 32, 256, 0, stream>>>(h, wsw, bemb, xb, xq);

    for (int l = 0; l < N_LAYERSC; l++) {
        k_aggregate<<<(N_NODESC * 16 + 255) / 256, 256, 0, stream>>>(xq, offs, esrc, cb);
        k_lgemm<<<NPAD / 64, 256, 0, stream>>>(
            xb, cb,
            wsw + IN_DIMC * HIDC + (size_t)l * 2 * HIDC * HIDC,
            bs + (size_t)l * HIDC, xq);
    }
    k_pool<<<N_GRAPHSC * 4, 256, 0, stream>>>(xb, gstart, hg);
    k_readout<<<N_GRAPHSC, 256, 0, stream>>>(hg, ppos, pneg, wfc, out);
}

// Round 14
// 456.780 us; speedup vs baseline: 1.1525x; 1.0523x over previous
//
#include <hip/hip_runtime.h>
#include <math.h>

#define N_NODESC 50000
#define NPAD 50048              // 1564 * 32
#define N_EDGESC 800000
#define N_GRAPHSC 64
#define IN_DIMC 128
#define HIDC 256
#define N_LAYERSC 4
#define EPSV 1e-12f

#define NBUCK 196               // buckets of 256 nodes
#define EPB 4096
#define NBLK1 196               // ceil(800000/4096)

typedef __attribute__((ext_vector_type(8))) short short8;
typedef __attribute__((ext_vector_type(4))) float floatx4;
typedef __attribute__((ext_vector_type(2))) float floatx2;

__device__ __forceinline__ unsigned short f2b(float f) {
    union { float f; unsigned u; } v; v.f = f;
    unsigned r = v.u + 0x7FFFu + ((v.u >> 16) & 1u);
    return (unsigned short)(r >> 16);
}
__device__ __forceinline__ float blo(unsigned u) { return __uint_as_float(u << 16); }
__device__ __forceinline__ float bhi(unsigned u) { return __uint_as_float(u & 0xFFFF0000u); }
__device__ __forceinline__ unsigned pkb(float a, float b) {
    return (unsigned)f2b(a) | ((unsigned)f2b(b) << 16);
}
__device__ __forceinline__ float b2f(unsigned short s) {
    return __uint_as_float((unsigned)s << 16);
}
__device__ __forceinline__ unsigned char f2q(float v) {
    return (unsigned char)(__builtin_amdgcn_cvt_pk_fp8_f32(v, v, 0, false) & 0xFF);
}
__device__ __forceinline__ void ldscp16(const void* g, void* l) {
    __builtin_amdgcn_global_load_lds(
        (const __attribute__((address_space(1))) unsigned int*)g,
        (__attribute__((address_space(3))) unsigned int*)l, 16, 0, 0);
}

// ---------------- graph boundaries via binary search (gid sorted) ----------------
__global__ __launch_bounds__(128) void k_gbounds(const int* __restrict__ gid,
        int* __restrict__ gstart) {
    int g = threadIdx.x;
    if (g > N_GRAPHSC) return;
    int lo = 0, hi = N_NODESC;
    while (lo < hi) {
        int mid = (lo + hi) >> 1;
        if (gid[mid] < g) lo = mid + 1; else hi = mid;
    }
    gstart[g] = lo;
}

// ---------------- CSR build, bucketed (bucket = dst>>8) ----------------
__global__ __launch_bounds__(256) void k_bcount(const int* __restrict__ dst,
        int* __restrict__ gbcnt) {
    __shared__ int bc[256];
    int t = threadIdx.x;
    bc[t] = 0;
    __syncthreads();
    int e0 = blockIdx.x * EPB;
    for (int i = t; i < EPB; i += 256) {
        int e = e0 + i;
        if (e < N_EDGESC) atomicAdd(&bc[dst[e] >> 8], 1);
    }
    __syncthreads();
    if (t < NBUCK && bc[t] > 0) atomicAdd(&gbcnt[t], bc[t]);
}

__global__ __launch_bounds__(256) void k_bscan(const int* __restrict__ gbcnt,
        int* __restrict__ boffB, int* __restrict__ gcurB) {
    __shared__ int s[256];
    int t = threadIdx.x;
    int v = (t < NBUCK) ? gbcnt[t] : 0;
    s[t] = v;
    __syncthreads();
    for (int d = 1; d < 256; d <<= 1) {
        int u = (t >= d) ? s[t - d] : 0;
        __syncthreads();
        s[t] += u;
        __syncthreads();
    }
    if (t < NBUCK) {
        int excl = s[t] - v;
        boffB[t] = excl;
        gcurB[t] = excl;
    }
    if (t == 0) boffB[NBUCK] = N_EDGESC;
}

__global__ __launch_bounds__(256) void k_bscatter(const int* __restrict__ src,
        const int* __restrict__ dst, int* __restrict__ gcurB,
        unsigned* __restrict__ ebpack) {
    __shared__ int bc[256];
    __shared__ int cur[256];
    int t = threadIdx.x;
    bc[t] = 0;
    __syncthreads();
    int e0 = blockIdx.x * EPB;
    for (int i = t; i < EPB; i += 256) {
        int e = e0 + i;
        if (e < N_EDGESC) atomicAdd(&bc[dst[e] >> 8], 1);
    }
    __syncthreads();
    if (t < NBUCK)
        cur[t] = (bc[t] > 0) ? atomicAdd(&gcurB[t], bc[t]) : 0;
    __syncthreads();
    for (int i = t; i < EPB; i += 256) {
        int e = e0 + i;
        if (e < N_EDGESC) {
            int d = dst[e];
            int b = d >> 8;
            int pos = atomicAdd(&cur[b], 1);
            ebpack[pos] = (unsigned)src[e] | ((unsigned)(d & 255) << 16);
        }
    }
}

__global__ __launch_bounds__(256) void k_bbuild(const unsigned* __restrict__ ebpack,
        const int* __restrict__ boffB, int* __restrict__ offs,
        unsigned short* __restrict__ esrc) {
    __shared__ int deg[256];
    __shared__ int lofs[256];
    __shared__ unsigned short img[12288];
    int b = blockIdx.x;
    int t = threadIdx.x;
    int bbase = boffB[b];
    int cnt = boffB[b + 1] - bbase;
    deg[t] = 0;
    __syncthreads();
    for (int i = t; i < cnt; i += 256)
        atomicAdd(&deg[ebpack[bbase + i] >> 16], 1);
    __syncthreads();
    int v = deg[t];
    lofs[t] = v;
    __syncthreads();
    for (int d = 1; d < 256; d <<= 1) {
        int u = (t >= d) ? lofs[t - d] : 0;
        __syncthreads();
        lofs[t] += u;
        __syncthreads();
    }
    int excl = lofs[t] - v;
    int node = b * 256 + t;
    if (node < N_NODESC) offs[node] = bbase + excl;
    if (b == NBUCK - 1 && t == 0) offs[N_NODESC] = N_EDGESC;
    deg[t] = excl;
    __syncthreads();
    for (int i = t; i < cnt; i += 256) {
        unsigned p = ebpack[bbase + i];
        int pos = atomicAdd(&deg[p >> 16], 1);
        img[pos] = (unsigned short)(p & 0xFFFF);
    }
    __syncthreads();
    for (int i = t; i < cnt; i += 256)
        esrc[bbase + i] = img[i];
}

// ---------------- weight convert + swizzle to MFMA B-fragment order ----------------
__global__ __launch_bounds__(256) void k_wconv(const float* __restrict__ Wemb,
        const float* __restrict__ Ws, unsigned short* __restrict__ wsw) {
    int idx = blockIdx.x * 256 + threadIdx.x;
    const int EMB = IN_DIMC * HIDC;           // 32768
    const int LYR = 2 * HIDC * HIDC;          // 131072
    if (idx >= EMB + N_LAYERSC * LYR) return;
    float val; int k, n; unsigned short* basep;
    if (idx < EMB) {
        k = idx >> 8; n = idx & 255;
        val = Wemb[idx];
        basep = wsw;
    } else {
        int r = idx - EMB;
        int l = r >> 17;
        int r2 = r & (LYR - 1);
        k = r2 >> 8; n = r2 & 255;
        val = Ws[r];
        basep = wsw + EMB + l * LYR;
    }
    int off = (((k >> 5) * 16 + (n >> 4)) * 64 + ((((k >> 3) & 3) << 4) | (n & 15))) * 8 + (k & 7);
    basep[off] = f2b(val);
}

// ---------------- per-node mean aggregation: fp8 gather (32 lanes/node, uint2) ----------------
__global__ __launch_bounds__(256) void k_aggregate(const unsigned char* __restrict__ xq,
        const int* __restrict__ offs, const unsigned short* __restrict__ esrc,
        unsigned short* __restrict__ cb) {
    int gidx = blockIdx.x * 256 + threadIdx.x;
    int node = gidx >> 5;
    int lane = threadIdx.x & 31;
    if (node >= N_NODESC) return;
    int beg = offs[node], end = offs[node + 1];
    float a[8];
    #pragma unroll
    for (int j = 0; j < 8; j++) a[j] = 0.f;
    size_t loff = (size_t)lane * 8;
    int e = beg;
    #define ACC8(v) do { \
        floatx2 t0 = __builtin_amdgcn_cvt_pk_f32_fp8((v).x, false); \
        floatx2 t1 = __builtin_amdgcn_cvt_pk_f32_fp8((v).x, true);  \
        floatx2 t2 = __builtin_amdgcn_cvt_pk_f32_fp8((v).y, false); \
        floatx2 t3 = __builtin_amdgcn_cvt_pk_f32_fp8((v).y, true);  \
        a[0] += t0.x; a[1] += t0.y; a[2] += t1.x; a[3] += t1.y;     \
        a[4] += t2.x; a[5] += t2.y; a[6] += t3.x; a[7] += t3.y;     \
    } while (0)
    for (; e + 8 <= end; e += 8) {
        int sidx[8];
        #pragma unroll
        for (int j = 0; j < 8; j++) sidx[j] = esrc[e + j];
        uint2 v[8];
        #pragma unroll
        for (int j = 0; j < 8; j++)
            v[j] = *(const uint2*)(xq + (size_t)sidx[j] * HIDC + loff);
        #pragma unroll
        for (int j = 0; j < 8; j++) ACC8(v[j]);
    }
    if (e + 4 <= end) {
        int sidx[4];
        #pragma unroll
        for (int j = 0; j < 4; j++) sidx[j] = esrc[e + j];
        uint2 v[4];
        #pragma unroll
        for (int j = 0; j < 4; j++)
            v[j] = *(const uint2*)(xq + (size_t)sidx[j] * HIDC + loff);
        #pragma unroll
        for (int j = 0; j < 4; j++) ACC8(v[j]);
        e += 4;
    }
    for (; e < end; e++) {
        uint2 v = *(const uint2*)(xq + (size_t)esrc[e] * HIDC + loff);
        ACC8(v);
    }
    #undef ACC8
    float w = 1.0f / (float)max(end - beg, 1);
    uint4 o;
    o.x = pkb(a[0] * w, a[1] * w);
    o.y = pkb(a[2] * w, a[3] * w);
    o.z = pkb(a[4] * w, a[5] * w);
    o.w = pkb(a[6] * w, a[7] * w);
    *(uint4*)(cb + (size_t)node * HIDC + loff) = o;
}

// ---------------- layer GEMM: 32-row blocks, A-panel in LDS via global_load_lds ----------------
// 1564 blocks (~6/CU) so staging/barrier drain of one block overlaps MFMA of others.
__global__ __launch_bounds__(256, 6) void k_lgemm(unsigned short* __restrict__ xb,
        const unsigned short* __restrict__ cbr, const unsigned short* __restrict__ wb,
        const float* __restrict__ bias, unsigned char* __restrict__ xq) {
    __shared__ unsigned short As[8192];   // 16 KB panel (32 rows x 512 B)
    __shared__ float rs[32];
    int tid = threadIdx.x;
    int w = tid >> 6;
    int lane = tid & 63;
    int quad = lane >> 4;
    int l15 = lane & 15;
    int row0 = blockIdx.x * 32;

    floatx4 acc[2][4];
    #pragma unroll
    for (int mt = 0; mt < 2; mt++)
        #pragma unroll
        for (int n = 0; n < 4; n++)
            acc[mt][n] = (floatx4){0.f, 0.f, 0.f, 0.f};

    const unsigned short* bp = wb + ((size_t)(w * 4) * 64 + lane) * 8;  // step stride 8192

    int sboff = w * 4096 + lane * 16;   // this lane's first LDS byte (i=0)
    #pragma unroll
    for (int phase = 0; phase < 2; phase++) {
        const unsigned short* srcb = (phase == 0) ? (const unsigned short*)xb : cbr;
        if (phase == 1) __syncthreads();   // all phase-0 reads done before overwrite
        #pragma unroll
        for (int i = 0; i < 4; i++) {
            int ldsoff = sboff + i * 1024;         // bytes
            int r = ldsoff >> 9;                   // row 0..31
            int ch = (ldsoff & 511) >> 4;          // physical 16B chunk
            int lc = ch ^ (r & 15);                // logical chunk (XOR swizzle)
            const unsigned short* g = srcb + (size_t)(row0 + r) * HIDC + lc * 8;
            ldscp16(g, &As[w * 2048 + i * 512]);   // lds base wave-uniform
        }
        __syncthreads();   // drains vmcnt -> panel visible

        #pragma unroll
        for (int ks = 0; ks < 8; ks++) {
            short8 afr[2], bfr[4];
            #pragma unroll
            for (int mt = 0; mt < 2; mt++) {
                int row = mt * 16 + l15;
                int phys = ((ks << 2) | quad) ^ l15;
                afr[mt] = *(const short8*)&As[row * 256 + phys * 8];
            }
            const unsigned short* wp = bp + (size_t)(phase * 8 + ks) * 8192;
            #pragma unroll
            for (int n = 0; n < 4; n++)
                bfr[n] = *(const short8*)(wp + n * 512);
            #pragma unroll
            for (int mt = 0; mt < 2; mt++)
                #pragma unroll
                for (int n = 0; n < 4; n++)
                    acc[mt][n] = __builtin_amdgcn_mfma_f32_16x16x32_bf16(
                        afr[mt], bfr[n], acc[mt][n], 0, 0, 0);
        }
    }

    float bv[4];
    #pragma unroll
    for (int n = 0; n < 4; n++) bv[n] = bias[w * 64 + n * 16 + l15];
    #pragma unroll
    for (int mt = 0; mt < 2; mt++)
        #pragma unroll
        for (int n = 0; n < 4; n++)
            #pragma unroll
            for (int r = 0; r < 4; r++)
                acc[mt][n][r] += bv[n];

    // row L2-norm across 4 col-waves
    __syncthreads();
    if (tid < 32) rs[tid] = 0.f;
    __syncthreads();
    #pragma unroll
    for (int mt = 0; mt < 2; mt++) {
        #pragma unroll
        for (int r = 0; r < 4; r++) {
            float p = acc[mt][0][r] * acc[mt][0][r] + acc[mt][1][r] * acc[mt][1][r]
                    + acc[mt][2][r] * acc[mt][2][r] + acc[mt][3][r] * acc[mt][3][r];
            p += __shfl_xor(p, 1);
            p += __shfl_xor(p, 2);
            p += __shfl_xor(p, 4);
            p += __shfl_xor(p, 8);
            if (l15 == 0) atomicAdd(&rs[mt * 16 + quad * 4 + r], p);
        }
    }
    __syncthreads();

    #pragma unroll
    for (int mt = 0; mt < 2; mt++) {
        #pragma unroll
        for (int r = 0; r < 4; r++) {
            int row = row0 + mt * 16 + quad * 4 + r;
            if (row < N_NODESC) {
                float inv = 1.0f / fmaxf(sqrtf(rs[mt * 16 + quad * 4 + r]), EPSV);
                #pragma unroll
                for (int n = 0; n < 4; n++) {
                    int col = w * 64 + n * 16 + l15;
                    size_t idx = (size_t)row * HIDC + col;
                    float xo = b2f(xb[idx]);
                    float v = fmaxf(acc[mt][n][r] * inv, 0.f);
                    float nv = xo + v;
                    xb[idx] = f2b(nv);
                    xq[idx] = f2q(nv);
                }
            }
        }
    }
}

// ---------------- embed GEMM: 32-row blocks, direct fp32 frag loads ----------------
__global__ __launch_bounds__(256, 4) void k_egemm(const float* __restrict__ h,
        const unsigned short* __restrict__ wsw, const float* __restrict__ bias,
        unsigned short* __restrict__ xb, unsigned char* __restrict__ xq) {
    int tid = threadIdx.x;
    int wn = tid >> 6;
    int lane = tid & 63;
    int quad = lane >> 4;
    int l15 = lane & 15;
    int row0 = blockIdx.x * 32;

    floatx4 acc[2][4];
    #pragma unroll
    for (int mt = 0; mt < 2; mt++)
        #pragma unroll
        for (int n = 0; n < 4; n++)
            acc[mt][n] = (floatx4){0.f, 0.f, 0.f, 0.f};

    int r0 = row0 + l15;
    int r1 = row0 + 16 + l15;
    bool ok0 = r0 < N_NODESC, ok1 = r1 < N_NODESC;
    const float* h0 = h + (size_t)r0 * IN_DIMC + quad * 8;
    const float* h1 = h + (size_t)r1 * IN_DIMC + quad * 8;
    const unsigned short* bp = wsw + ((size_t)(wn * 4) * 64 + lane) * 8;

    #pragma unroll
    for (int ks = 0; ks < 4; ks++) {
        float4 f00 = ok0 ? *(const float4*)(h0 + ks * 32)     : (float4){0,0,0,0};
        float4 f01 = ok0 ? *(const float4*)(h0 + ks * 32 + 4) : (float4){0,0,0,0};
        float4 f10 = ok1 ? *(const float4*)(h1 + ks * 32)     : (float4){0,0,0,0};
        float4 f11 = ok1 ? *(const float4*)(h1 + ks * 32 + 4) : (float4){0,0,0,0};
        short8 afr[2], bfr[4];
        uint4 av;
        av.x = pkb(f00.x, f00.y); av.y = pkb(f00.z, f00.w);
        av.z = pkb(f01.x, f01.y); av.w = pkb(f01.z, f01.w);
        afr[0] = *(short8*)&av;
        av.x = pkb(f10.x, f10.y); av.y = pkb(f10.z, f10.w);
        av.z = pkb(f11.x, f11.y); av.w = pkb(f11.z, f11.w);
        afr[1] = *(short8*)&av;
        const unsigned short* wp = bp + (size_t)ks * 8192;
        #pragma unroll
        for (int n = 0; n < 4; n++)
            bfr[n] = *(const short8*)(wp + n * 512);
        #pragma unroll
        for (int mt = 0; mt < 2; mt++)
            #pragma unroll
            for (int n = 0; n < 4; n++)
                acc[mt][n] = __builtin_amdgcn_mfma_f32_16x16x32_bf16(
                    afr[mt], bfr[n], acc[mt][n], 0, 0, 0);
    }

    float bv[4];
    #pragma unroll
    for (int n = 0; n < 4; n++) bv[n] = bias[wn * 64 + n * 16 + l15];
    #pragma unroll
    for (int mt = 0; mt < 2; mt++) {
        #pragma unroll
        for (int r = 0; r < 4; r++) {
            int row = row0 + mt * 16 + quad * 4 + r;
            if (row < N_NODESC) {
                #pragma unroll
                for (int n = 0; n < 4; n++) {
                    int col = wn * 64 + n * 16 + l15;
                    float v = acc[mt][n][r] + bv[n];
                    size_t idx = (size_t)row * HIDC + col;
                    xb[idx] = f2b(v);
                    xq[idx] = f2q(v);
                }
            }
        }
    }
}

// ---------------- graph mean-pool: 1 block per (graph, 64-col quarter) ----------------
__global__ __launch_bounds__(256) void k_pool(const unsigned short* __restrict__ xb,
        const int* __restrict__ gstart, float* __restrict__ hg) {
    __shared__ float red[256][8];
    int g = blockIdx.x >> 2;
    int cq = blockIdx.x & 3;
    int t = threadIdx.x;
    int cchunk = t & 7;
    int rgrp = t >> 3;
    int col0 = cq * 64 + cchunk * 8;
    int beg = gstart[g], end = gstart[g + 1];
    float a[8];
    #pragma unroll
    for (int j = 0; j < 8; j++) a[j] = 0.f;
    for (int r = beg + rgrp; r < end; r += 32) {
        uint4 v = *(const uint4*)(xb + (size_t)r * HIDC + col0);
        a[0] += blo(v.x); a[1] += bhi(v.x);
        a[2] += blo(v.y); a[3] += bhi(v.y);
        a[4] += blo(v.z); a[5] += bhi(v.z);
        a[6] += blo(v.w); a[7] += bhi(v.w);
    }
    #pragma unroll
    for (int j = 0; j < 8; j++) red[t][j] = a[j];
    __syncthreads();
    for (int d = 16; d >= 1; d >>= 1) {
        if (rgrp < d) {
            #pragma unroll
            for (int j = 0; j < 8; j++) red[t][j] += red[t + d * 8][j];
        }
        __syncthreads();
    }
    if (rgrp == 0) {
        float inv = 1.0f / (float)max(end - beg, 1);
        #pragma unroll
        for (int j = 0; j < 8; j++)
            hg[g * HIDC + col0 + j] = red[t][j] * inv;
    }
}

// ---------------- readout ----------------
__global__ __launch_bounds__(256) void k_readout(const float* __restrict__ hg,
        const float* __restrict__ ppos, const float* __restrict__ pneg,
        const float* __restrict__ wfc, float* __restrict__ out) {
    __shared__ float red[256];
    __shared__ float ss[10];
    int t = threadIdx.x;
    int g = blockIdx.x;
    float hgv = hg[g * HIDC + t];
    for (int p = 0; p < 10; p++) {
        const float* P = (p < 5) ? (ppos + p * HIDC) : (pneg + (p - 5) * HIDC);
        float d = hgv - P[t];
        red[t] = d * d;
        __syncthreads();
        for (int s2 = 128; s2 > 0; s2 >>= 1) {
            if (t < s2) red[t] += red[t + s2];
            __syncthreads();
        }
        if (t == 0) {
            float dd = red[0];
            ss[p] = logf((dd + 1.0f) / (dd + EPSV));
        }
        __syncthreads();
    }
    if (t == 0) {
        float y = 0.f;
        #pragma unroll
        for (int p = 0; p < 10; p++) y += ss[p] * wfc[p];
        out[g] = 1.0f / (1.0f + expf(-y));
    }
}

extern "C" void kernel_launch(void* const* d_in, const int* in_sizes, int n_in,
                              void* d_out, int out_size, void* d_ws, size_t ws_size,
                              hipStream_t stream) {
    const float* h    = (const float*)d_in[0];
    const int*   src  = (const int*)d_in[1];
    const int*   dst  = (const int*)d_in[2];
    const int*   gid  = (const int*)d_in[3];
    const float* Wemb = (const float*)d_in[4];
    const float* bemb = (const float*)d_in[5];
    const float* Ws   = (const float*)d_in[6];
    const float* bs   = (const float*)d_in[7];
    const float* ppos = (const float*)d_in[8];
    const float* pneg = (const float*)d_in[9];
    const float* wfc  = (const float*)d_in[10];
    float* out = (float*)d_out;

    char* ws = (char*)d_ws;
    size_t off = 0;
    auto alloc = [&](size_t bytes) {
        void* p = ws + off;
        off += (bytes + 255) & ~(size_t)255;
        return p;
    };
    unsigned short* xb     = (unsigned short*)alloc((size_t)NPAD * HIDC * 2);  // bf16 row-major
    unsigned char*  xq     = (unsigned char*)alloc((size_t)NPAD * HIDC);       // fp8 shadow
    unsigned short* cb     = (unsigned short*)alloc((size_t)NPAD * HIDC * 2);  // bf16 row-major
    unsigned short* wsw    = (unsigned short*)alloc((size_t)(IN_DIMC * HIDC + N_LAYERSC * 2 * HIDC * HIDC) * 2);
    int*            offs   = (int*)alloc((size_t)(N_NODESC + 1) * 4);
    unsigned short* esrc   = (unsigned short*)alloc((size_t)N_EDGESC * 2);
    unsigned*       ebpack = (unsigned*)alloc((size_t)N_EDGESC * 4);
    int*            gbcnt  = (int*)alloc((size_t)NBUCK * 4);
    int*            boffB  = (int*)alloc((size_t)(NBUCK + 1) * 4);
    int*            gcurB  = (int*)alloc((size_t)NBUCK * 4);
    int*            gstart = (int*)alloc((size_t)(N_GRAPHSC + 1) * 4);
    float*          hg     = (float*)alloc((size_t)N_GRAPHSC * HIDC * 4);
    (void)ws_size; (void)in_sizes; (void)n_in; (void)out_size;

    hipMemsetAsync(gbcnt, 0, (size_t)NBUCK * 4, stream);

    const int WTOT = IN_DIMC * HIDC + N_LAYERSC * 2 * HIDC * HIDC; // 557056
    k_wconv<<<(WTOT + 255) / 256, 256, 0, stream>>>(Wemb, Ws, wsw);
    k_gbounds<<<1, 128, 0, stream>>>(gid, gstart);
    k_bcount<<<NBLK1, 256, 0, stream>>>(dst, gbcnt);
    k_bscan<<<1, 256, 0, stream>>>(gbcnt, boffB, gcurB);
    k_bscatter<<<NBLK1, 256, 0, stream>>>(src, dst, gcurB, ebpack);
    k_bbuild<<<NBUCK, 256, 0, stream>>>(ebpack, boffB, offs, esrc);

    k_egemm<<<NPAD / 32, 256, 0, stream>>>(h, wsw, bemb, xb, xq);

    for (int l = 0; l < N_LAYERSC; l++) {
        k_aggregate<<<(N_NODESC * 32 + 255) / 256, 256, 0, stream>>>(xq, offs, esrc, cb);
        k_lgemm<<<NPAD / 32, 256, 0, stream>>>(
            xb, cb,
            wsw + IN_DIMC * HIDC + (size_t)l * 2 * HIDC * HIDC,
            bs + (size_t)l * HIDC, xq);
    }
    k_pool<<<N_GRAPHSC * 4, 256, 0, stream>>>(xb, gstart, hg);
    k_readout<<<N_GRAPHSC, 256, 0, stream>>>(hg, ppos, pneg, wfc, out);
}

// Round 15
// 439.552 us; speedup vs baseline: 1.1976x; 1.0392x over previous
//
#include <hip/hip_runtime.h>
#include <math.h>

#define N_NODESC 50000
#define NPAD 50048              // 1564 * 32
#define N_EDGESC 800000
#define N_GRAPHSC 64
#define IN_DIMC 128
#define HIDC 256
#define N_LAYERSC 4
#define EPSV 1e-12f

#define NBUCK 196               // buckets of 256 nodes
#define EPB 4096
#define NBLK1 196               // ceil(800000/4096)

typedef __attribute__((ext_vector_type(8))) short short8;
typedef __attribute__((ext_vector_type(4))) float floatx4;
typedef __attribute__((ext_vector_type(2))) float floatx2;

__device__ __forceinline__ unsigned short f2b(float f) {
    union { float f; unsigned u; } v; v.f = f;
    unsigned r = v.u + 0x7FFFu + ((v.u >> 16) & 1u);
    return (unsigned short)(r >> 16);
}
__device__ __forceinline__ float blo(unsigned u) { return __uint_as_float(u << 16); }
__device__ __forceinline__ float bhi(unsigned u) { return __uint_as_float(u & 0xFFFF0000u); }
__device__ __forceinline__ unsigned pkb(float a, float b) {
    return (unsigned)f2b(a) | ((unsigned)f2b(b) << 16);
}
__device__ __forceinline__ float b2f(unsigned short s) {
    return __uint_as_float((unsigned)s << 16);
}
__device__ __forceinline__ unsigned char f2q(float v) {
    return (unsigned char)(__builtin_amdgcn_cvt_pk_fp8_f32(v, v, 0, false) & 0xFF);
}
__device__ __forceinline__ unsigned pk4q(float a, float b, float c, float d) {
    unsigned lo = (unsigned)__builtin_amdgcn_cvt_pk_fp8_f32(a, b, 0, false) & 0xFFFFu;
    unsigned hi = (unsigned)__builtin_amdgcn_cvt_pk_fp8_f32(c, d, 0, false) << 16;
    return lo | hi;
}
__device__ __forceinline__ void ldscp16(const void* g, void* l) {
    __builtin_amdgcn_global_load_lds(
        (const __attribute__((address_space(1))) unsigned int*)g,
        (__attribute__((address_space(3))) unsigned int*)l, 16, 0, 0);
}

// ---------------- graph boundaries via binary search (gid sorted) ----------------
__global__ __launch_bounds__(128) void k_gbounds(const int* __restrict__ gid,
        int* __restrict__ gstart) {
    int g = threadIdx.x;
    if (g > N_GRAPHSC) return;
    int lo = 0, hi = N_NODESC;
    while (lo < hi) {
        int mid = (lo + hi) >> 1;
        if (gid[mid] < g) lo = mid + 1; else hi = mid;
    }
    gstart[g] = lo;
}

// ---------------- CSR build, bucketed (bucket = dst>>8) ----------------
__global__ __launch_bounds__(256) void k_bcount(const int* __restrict__ dst,
        int* __restrict__ gbcnt) {
    __shared__ int bc[256];
    int t = threadIdx.x;
    bc[t] = 0;
    __syncthreads();
    int e0 = blockIdx.x * EPB;
    for (int i = t; i < EPB; i += 256) {
        int e = e0 + i;
        if (e < N_EDGESC) atomicAdd(&bc[dst[e] >> 8], 1);
    }
    __syncthreads();
    if (t < NBUCK && bc[t] > 0) atomicAdd(&gbcnt[t], bc[t]);
}

__global__ __launch_bounds__(256) void k_bscan(const int* __restrict__ gbcnt,
        int* __restrict__ boffB, int* __restrict__ gcurB) {
    __shared__ int s[256];
    int t = threadIdx.x;
    int v = (t < NBUCK) ? gbcnt[t] : 0;
    s[t] = v;
    __syncthreads();
    for (int d = 1; d < 256; d <<= 1) {
        int u = (t >= d) ? s[t - d] : 0;
        __syncthreads();
        s[t] += u;
        __syncthreads();
    }
    if (t < NBUCK) {
        int excl = s[t] - v;
        boffB[t] = excl;
        gcurB[t] = excl;
    }
    if (t == 0) boffB[NBUCK] = N_EDGESC;
}

__global__ __launch_bounds__(256) void k_bscatter(const int* __restrict__ src,
        const int* __restrict__ dst, int* __restrict__ gcurB,
        unsigned* __restrict__ ebpack) {
    __shared__ int bc[256];
    __shared__ int cur[256];
    int t = threadIdx.x;
    bc[t] = 0;
    __syncthreads();
    int e0 = blockIdx.x * EPB;
    for (int i = t; i < EPB; i += 256) {
        int e = e0 + i;
        if (e < N_EDGESC) atomicAdd(&bc[dst[e] >> 8], 1);
    }
    __syncthreads();
    if (t < NBUCK)
        cur[t] = (bc[t] > 0) ? atomicAdd(&gcurB[t], bc[t]) : 0;
    __syncthreads();
    for (int i = t; i < EPB; i += 256) {
        int e = e0 + i;
        if (e < N_EDGESC) {
            int d = dst[e];
            int b = d >> 8;
            int pos = atomicAdd(&cur[b], 1);
            ebpack[pos] = (unsigned)src[e] | ((unsigned)(d & 255) << 16);
        }
    }
}

__global__ __launch_bounds__(256) void k_bbuild(const unsigned* __restrict__ ebpack,
        const int* __restrict__ boffB, int* __restrict__ offs,
        unsigned short* __restrict__ esrc) {
    __shared__ int deg[256];
    __shared__ int lofs[256];
    __shared__ unsigned short img[12288];
    int b = blockIdx.x;
    int t = threadIdx.x;
    int bbase = boffB[b];
    int cnt = boffB[b + 1] - bbase;
    deg[t] = 0;
    __syncthreads();
    for (int i = t; i < cnt; i += 256)
        atomicAdd(&deg[ebpack[bbase + i] >> 16], 1);
    __syncthreads();
    int v = deg[t];
    lofs[t] = v;
    __syncthreads();
    for (int d = 1; d < 256; d <<= 1) {
        int u = (t >= d) ? lofs[t - d] : 0;
        __syncthreads();
        lofs[t] += u;
        __syncthreads();
    }
    int excl = lofs[t] - v;
    int node = b * 256 + t;
    if (node < N_NODESC) offs[node] = bbase + excl;
    if (b == NBUCK - 1 && t == 0) offs[N_NODESC] = N_EDGESC;
    deg[t] = excl;
    __syncthreads();
    for (int i = t; i < cnt; i += 256) {
        unsigned p = ebpack[bbase + i];
        int pos = atomicAdd(&deg[p >> 16], 1);
        img[pos] = (unsigned short)(p & 0xFFFF);
    }
    __syncthreads();
    for (int i = t; i < cnt; i += 256)
        esrc[bbase + i] = img[i];
}

// ---------------- weight convert + swizzle to MFMA B-fragment order ----------------
__global__ __launch_bounds__(256) void k_wconv(const float* __restrict__ Wemb,
        const float* __restrict__ Ws, unsigned short* __restrict__ wsw) {
    int idx = blockIdx.x * 256 + threadIdx.x;
    const int EMB = IN_DIMC * HIDC;           // 32768
    const int LYR = 2 * HIDC * HIDC;          // 131072
    if (idx >= EMB + N_LAYERSC * LYR) return;
    float val; int k, n; unsigned short* basep;
    if (idx < EMB) {
        k = idx >> 8; n = idx & 255;
        val = Wemb[idx];
        basep = wsw;
    } else {
        int r = idx - EMB;
        int l = r >> 17;
        int r2 = r & (LYR - 1);
        k = r2 >> 8; n = r2 & 255;
        val = Ws[r];
        basep = wsw + EMB + l * LYR;
    }
    int off = (((k >> 5) * 16 + (n >> 4)) * 64 + ((((k >> 3) & 3) << 4) | (n & 15))) * 8 + (k & 7);
    basep[off] = f2b(val);
}

// ---------------- per-node mean aggregation: fp8 gather -> fp8 output ----------------
__global__ __launch_bounds__(256) void k_aggregate(const unsigned char* __restrict__ xq,
        const int* __restrict__ offs, const unsigned short* __restrict__ esrc,
        unsigned char* __restrict__ cq) {
    int gidx = blockIdx.x * 256 + threadIdx.x;
    int node = gidx >> 5;
    int lane = threadIdx.x & 31;
    if (node >= N_NODESC) return;
    int beg = offs[node], end = offs[node + 1];
    float a[8];
    #pragma unroll
    for (int j = 0; j < 8; j++) a[j] = 0.f;
    size_t loff = (size_t)lane * 8;
    int e = beg;
    #define ACC8(v) do { \
        floatx2 t0 = __builtin_amdgcn_cvt_pk_f32_fp8((v).x, false); \
        floatx2 t1 = __builtin_amdgcn_cvt_pk_f32_fp8((v).x, true);  \
        floatx2 t2 = __builtin_amdgcn_cvt_pk_f32_fp8((v).y, false); \
        floatx2 t3 = __builtin_amdgcn_cvt_pk_f32_fp8((v).y, true);  \
        a[0] += t0.x; a[1] += t0.y; a[2] += t1.x; a[3] += t1.y;     \
        a[4] += t2.x; a[5] += t2.y; a[6] += t3.x; a[7] += t3.y;     \
    } while (0)
    for (; e + 8 <= end; e += 8) {
        int sidx[8];
        #pragma unroll
        for (int j = 0; j < 8; j++) sidx[j] = esrc[e + j];
        uint2 v[8];
        #pragma unroll
        for (int j = 0; j < 8; j++)
            v[j] = *(const uint2*)(xq + (size_t)sidx[j] * HIDC + loff);
        #pragma unroll
        for (int j = 0; j < 8; j++) ACC8(v[j]);
    }
    if (e + 4 <= end) {
        int sidx[4];
        #pragma unroll
        for (int j = 0; j < 4; j++) sidx[j] = esrc[e + j];
        uint2 v[4];
        #pragma unroll
        for (int j = 0; j < 4; j++)
            v[j] = *(const uint2*)(xq + (size_t)sidx[j] * HIDC + loff);
        #pragma unroll
        for (int j = 0; j < 4; j++) ACC8(v[j]);
        e += 4;
    }
    for (; e < end; e++) {
        uint2 v = *(const uint2*)(xq + (size_t)esrc[e] * HIDC + loff);
        ACC8(v);
    }
    #undef ACC8
    float w = 1.0f / (float)max(end - beg, 1);
    uint2 o;
    o.x = pk4q(a[0] * w, a[1] * w, a[2] * w, a[3] * w);
    o.y = pk4q(a[4] * w, a[5] * w, a[6] * w, a[7] * w);
    *(uint2*)(cq + (size_t)node * HIDC + loff) = o;
}

// ---------------- layer GEMM: dual 16KB panels, single barrier ----------------
// panelA <- xb rows (async global_load_lds); panelC <- cq fp8 rows (manual load +
// cvt->bf16 + swizzled ds_write, overlaps the async DMA). One __syncthreads, then
// 16 K-steps (8 per panel). Epilogue: bias, row L2-norm, relu, residual -> xb + xq.
__global__ __launch_bounds__(256, 4) void k_lgemm(unsigned short* __restrict__ xb,
        const unsigned char* __restrict__ cq, const unsigned short* __restrict__ wb,
        const float* __restrict__ bias, unsigned char* __restrict__ xq) {
    __shared__ unsigned short panelA[8192];   // 16 KB (32 rows x 512 B, swizzled)
    __shared__ unsigned short panelC[8192];   // 16 KB
    __shared__ float rs[32];
    int tid = threadIdx.x;
    int w = tid >> 6;
    int lane = tid & 63;
    int quad = lane >> 4;
    int l15 = lane & 15;
    int row0 = blockIdx.x * 32;

    // phase-0: async stage xb rows -> panelA
    {
        int sboff = w * 4096 + lane * 16;   // byte offset of this lane's first copy
        #pragma unroll
        for (int i = 0; i < 4; i++) {
            int ldsoff = sboff + i * 1024;
            int r = ldsoff >> 9;
            int ch = (ldsoff & 511) >> 4;
            int lc = ch ^ (r & 15);
            const unsigned short* g = (const unsigned short*)xb + (size_t)(row0 + r) * HIDC + lc * 8;
            ldscp16(g, &panelA[w * 2048 + i * 512]);
        }
    }
    // phase-1: manual stage cq (fp8) -> bf16 panelC (overlaps the DMA above)
    {
        int r = tid >> 3;        // 0..31
        int seg = tid & 7;       // 32 fp8 cols each
        const uint4* cp = (const uint4*)(cq + (size_t)(row0 + r) * HIDC + seg * 32);
        uint4 c0 = cp[0];
        uint4 c1 = cp[1];
        #define CVT16B(u0, u1, j) do { \
            floatx2 p0 = __builtin_amdgcn_cvt_pk_f32_fp8((u0), false); \
            floatx2 p1 = __builtin_amdgcn_cvt_pk_f32_fp8((u0), true);  \
            floatx2 p2 = __builtin_amdgcn_cvt_pk_f32_fp8((u1), false); \
            floatx2 p3 = __builtin_amdgcn_cvt_pk_f32_fp8((u1), true);  \
            uint4 ov; \
            ov.x = pkb(p0.x, p0.y); ov.y = pkb(p1.x, p1.y); \
            ov.z = pkb(p2.x, p2.y); ov.w = pkb(p3.x, p3.y); \
            int lc = seg * 4 + (j); \
            int phys = lc ^ (r & 15); \
            *(uint4*)&panelC[r * 256 + phys * 8] = ov; \
        } while (0)
        CVT16B(c0.x, c0.y, 0);
        CVT16B(c0.z, c0.w, 1);
        CVT16B(c1.x, c1.y, 2);
        CVT16B(c1.z, c1.w, 3);
        #undef CVT16B
    }
    __syncthreads();   // drains vmcnt (DMA) + lgkm (ds_write) -> both panels ready

    floatx4 acc[2][4];
    #pragma unroll
    for (int mt = 0; mt < 2; mt++)
        #pragma unroll
        for (int n = 0; n < 4; n++)
            acc[mt][n] = (floatx4){0.f, 0.f, 0.f, 0.f};

    const unsigned short* bp = wb + ((size_t)(w * 4) * 64 + lane) * 8;  // step stride 8192

    #pragma unroll
    for (int st = 0; st < 16; st++) {
        const unsigned short* pan = (st < 8) ? panelA : panelC;
        int ks = st & 7;
        short8 afr[2], bfr[4];
        #pragma unroll
        for (int mt = 0; mt < 2; mt++) {
            int row = mt * 16 + l15;
            int phys = ((ks << 2) | quad) ^ l15;
            afr[mt] = *(const short8*)&pan[row * 256 + phys * 8];
        }
        const unsigned short* wp = bp + (size_t)st * 8192;
        #pragma unroll
        for (int n = 0; n < 4; n++)
            bfr[n] = *(const short8*)(wp + n * 512);
        #pragma unroll
        for (int mt = 0; mt < 2; mt++)
            #pragma unroll
            for (int n = 0; n < 4; n++)
                acc[mt][n] = __builtin_amdgcn_mfma_f32_16x16x32_bf16(
                    afr[mt], bfr[n], acc[mt][n], 0, 0, 0);
    }

    float bv[4];
    #pragma unroll
    for (int n = 0; n < 4; n++) bv[n] = bias[w * 64 + n * 16 + l15];
    #pragma unroll
    for (int mt = 0; mt < 2; mt++)
        #pragma unroll
        for (int n = 0; n < 4; n++)
            #pragma unroll
            for (int r = 0; r < 4; r++)
                acc[mt][n][r] += bv[n];

    // row L2-norm across 4 col-waves
    __syncthreads();
    if (tid < 32) rs[tid] = 0.f;
    __syncthreads();
    #pragma unroll
    for (int mt = 0; mt < 2; mt++) {
        #pragma unroll
        for (int r = 0; r < 4; r++) {
            float p = acc[mt][0][r] * acc[mt][0][r] + acc[mt][1][r] * acc[mt][1][r]
                    + acc[mt][2][r] * acc[mt][2][r] + acc[mt][3][r] * acc[mt][3][r];
            p += __shfl_xor(p, 1);
            p += __shfl_xor(p, 2);
            p += __shfl_xor(p, 4);
            p += __shfl_xor(p, 8);
            if (l15 == 0) atomicAdd(&rs[mt * 16 + quad * 4 + r], p);
        }
    }
    __syncthreads();

    #pragma unroll
    for (int mt = 0; mt < 2; mt++) {
        #pragma unroll
        for (int r = 0; r < 4; r++) {
            int row = row0 + mt * 16 + quad * 4 + r;
            if (row < N_NODESC) {
                float inv = 1.0f / fmaxf(sqrtf(rs[mt * 16 + quad * 4 + r]), EPSV);
                #pragma unroll
                for (int n = 0; n < 4; n++) {
                    int col = w * 64 + n * 16 + l15;
                    size_t idx = (size_t)row * HIDC + col;
                    float xo = b2f(xb[idx]);
                    float v = fmaxf(acc[mt][n][r] * inv, 0.f);
                    float nv = xo + v;
                    xb[idx] = f2b(nv);
                    xq[idx] = f2q(nv);
                }
            }
        }
    }
}

// ---------------- embed GEMM: 32-row blocks, direct fp32 frag loads ----------------
__global__ __launch_bounds__(256, 4) void k_egemm(const float* __restrict__ h,
        const unsigned short* __restrict__ wsw, const float* __restrict__ bias,
        unsigned short* __restrict__ xb, unsigned char* __restrict__ xq) {
    int tid = threadIdx.x;
    int wn = tid >> 6;
    int lane = tid & 63;
    int quad = lane >> 4;
    int l15 = lane & 15;
    int row0 = blockIdx.x * 32;

    floatx4 acc[2][4];
    #pragma unroll
    for (int mt = 0; mt < 2; mt++)
        #pragma unroll
        for (int n = 0; n < 4; n++)
            acc[mt][n] = (floatx4){0.f, 0.f, 0.f, 0.f};

    int r0 = row0 + l15;
    int r1 = row0 + 16 + l15;
    bool ok0 = r0 < N_NODESC, ok1 = r1 < N_NODESC;
    const float* h0 = h + (size_t)r0 * IN_DIMC + quad * 8;
    const float* h1 = h + (size_t)r1 * IN_DIMC + quad * 8;
    const unsigned short* bp = wsw + ((size_t)(wn * 4) * 64 + lane) * 8;

    #pragma unroll
    for (int ks = 0; ks < 4; ks++) {
        float4 f00 = ok0 ? *(const float4*)(h0 + ks * 32)     : (float4){0,0,0,0};
        float4 f01 = ok0 ? *(const float4*)(h0 + ks * 32 + 4) : (float4){0,0,0,0};
        float4 f10 = ok1 ? *(const float4*)(h1 + ks * 32)     : (float4){0,0,0,0};
        float4 f11 = ok1 ? *(const float4*)(h1 + ks * 32 + 4) : (float4){0,0,0,0};
        short8 afr[2], bfr[4];
        uint4 av;
        av.x = pkb(f00.x, f00.y); av.y = pkb(f00.z, f00.w);
        av.z = pkb(f01.x, f01.y); av.w = pkb(f01.z, f01.w);
        afr[0] = *(short8*)&av;
        av.x = pkb(f10.x, f10.y); av.y = pkb(f10.z, f10.w);
        av.z = pkb(f11.x, f11.y); av.w = pkb(f11.z, f11.w);
        afr[1] = *(short8*)&av;
        const unsigned short* wp = bp + (size_t)ks * 8192;
        #pragma unroll
        for (int n = 0; n < 4; n++)
            bfr[n] = *(const short8*)(wp + n * 512);
        #pragma unroll
        for (int mt = 0; mt < 2; mt++)
            #pragma unroll
            for (int n = 0; n < 4; n++)
                acc[mt][n] = __builtin_amdgcn_mfma_f32_16x16x32_bf16(
                    afr[mt], bfr[n], acc[mt][n], 0, 0, 0);
    }

    float bv[4];
    #pragma unroll
    for (int n = 0; n < 4; n++) bv[n] = bias[wn * 64 + n * 16 + l15];
    #pragma unroll
    for (int mt = 0; mt < 2; mt++) {
        #pragma unroll
        for (int r = 0; r < 4; r++) {
            int row = row0 + mt * 16 + quad * 4 + r;
            if (row < N_NODESC) {
                #pragma unroll
                for (int n = 0; n < 4; n++) {
                    int col = wn * 64 + n * 16 + l15;
                    float v = acc[mt][n][r] + bv[n];
                    size_t idx = (size_t)row * HIDC + col;
                    xb[idx] = f2b(v);
                    xq[idx] = f2q(v);
                }
            }
        }
    }
}

// ---------------- graph mean-pool: 1 block per (graph, 64-col quarter) ----------------
__global__ __launch_bounds__(256) void k_pool(const unsigned short* __restrict__ xb,
        const int* __restrict__ gstart, float* __restrict__ hg) {
    __shared__ float red[256][8];
    int g = blockIdx.x >> 2;
    int cq = blockIdx.x & 3;
    int t = threadIdx.x;
    int cchunk = t & 7;
    int rgrp = t >> 3;
    int col0 = cq * 64 + cchunk * 8;
    int beg = gstart[g], end = gstart[g + 1];
    float a[8];
    #pragma unroll
    for (int j = 0; j < 8; j++) a[j] = 0.f;
    for (int r = beg + rgrp; r < end; r += 32) {
        uint4 v = *(const uint4*)(xb + (size_t)r * HIDC + col0);
        a[0] += blo(v.x); a[1] += bhi(v.x);
        a[2] += blo(v.y); a[3] += bhi(v.y);
        a[4] += blo(v.z); a[5] += bhi(v.z);
        a[6] += blo(v.w); a[7] += bhi(v.w);
    }
    #pragma unroll
    for (int j = 0; j < 8; j++) red[t][j] = a[j];
    __syncthreads();
    for (int d = 16; d >= 1; d >>= 1) {
        if (rgrp < d) {
            #pragma unroll
            for (int j = 0; j < 8; j++) red[t][j] += red[t + d * 8][j];
        }
        __syncthreads();
    }
    if (rgrp == 0) {
        float inv = 1.0f / (float)max(end - beg, 1);
        #pragma unroll
        for (int j = 0; j < 8; j++)
            hg[g * HIDC + col0 + j] = red[t][j] * inv;
    }
}

// ---------------- readout ----------------
__global__ __launch_bounds__(256) void k_readout(const float* __restrict__ hg,
        const float* __restrict__ ppos, const float* __restrict__ pneg,
        const float* __restrict__ wfc, float* __restrict__ out) {
    __shared__ float red[256];
    __shared__ float ss[10];
    int t = threadIdx.x;
    int g = blockIdx.x;
    float hgv = hg[g * HIDC + t];
    for (int p = 0; p < 10; p++) {
        const float* P = (p < 5) ? (ppos + p * HIDC) : (pneg + (p - 5) * HIDC);
        float d = hgv - P[t];
        red[t] = d * d;
        __syncthreads();
        for (int s2 = 128; s2 > 0; s2 >>= 1) {
            if (t < s2) red[t] += red[t + s2];
            __syncthreads();
        }
        if (t == 0) {
            float dd = red[0];
            ss[p] = logf((dd + 1.0f) / (dd + EPSV));
        }
        __syncthreads();
    }
    if (t == 0) {
        float y = 0.f;
        #pragma unroll
        for (int p = 0; p < 10; p++) y += ss[p] * wfc[p];
        out[g] = 1.0f / (1.0f + expf(-y));
    }
}

extern "C" void kernel_launch(void* const* d_in, const int* in_sizes, int n_in,
                              void* d_out, int out_size, void* d_ws, size_t ws_size,
                              hipStream_t stream) {
    const float* h    = (const float*)d_in[0];
    const int*   src  = (const int*)d_in[1];
    const int*   dst  = (const int*)d_in[2];
    const int*   gid  = (const int*)d_in[3];
    const float* Wemb = (const float*)d_in[4];
    const float* bemb = (const float*)d_in[5];
    const float* Ws   = (const float*)d_in[6];
    const float* bs   = (const float*)d_in[7];
    const float* ppos = (const float*)d_in[8];
    const float* pneg = (const float*)d_in[9];
    const float* wfc  = (const float*)d_in[10];
    float* out = (float*)d_out;

    char* ws = (char*)d_ws;
    size_t off = 0;
    auto alloc = [&](size_t bytes) {
        void* p = ws + off;
        off += (bytes + 255) & ~(size_t)255;
        return p;
    };
    unsigned short* xb     = (unsigned short*)alloc((size_t)NPAD * HIDC * 2);  // bf16 row-major
    unsigned char*  xq     = (unsigned char*)alloc((size_t)NPAD * HIDC);       // fp8 shadow
    unsigned char*  cq     = (unsigned char*)alloc((size_t)NPAD * HIDC);       // fp8 aggregate out
    unsigned short* wsw    = (unsigned short*)alloc((size_t)(IN_DIMC * HIDC + N_LAYERSC * 2 * HIDC * HIDC) * 2);
    int*            offs   = (int*)alloc((size_t)(N_NODESC + 1) * 4);
    unsigned short* esrc   = (unsigned short*)alloc((size_t)N_EDGESC * 2);
    unsigned*       ebpack = (unsigned*)alloc((size_t)N_EDGESC * 4);
    int*            gbcnt  = (int*)alloc((size_t)NBUCK * 4);
    int*            boffB  = (int*)alloc((size_t)(NBUCK + 1) * 4);
    int*            gcurB  = (int*)alloc((size_t)NBUCK * 4);
    int*            gstart = (int*)alloc((size_t)(N_GRAPHSC + 1) * 4);
    float*          hg     = (float*)alloc((size_t)N_GRAPHSC * HIDC * 4);
    (void)ws_size; (void)in_sizes; (void)n_in; (void)out_size;

    hipMemsetAsync(gbcnt, 0, (size_t)NBUCK * 4, stream);

    const int WTOT = IN_DIMC * HIDC + N_LAYERSC * 2 * HIDC * HIDC; // 557056
    k_wconv<<<(WTOT + 255) / 256, 256, 0, stream>>>(Wemb, Ws, wsw);
    k_gbounds<<<1, 128, 0, stream>>>(gid, gstart);
    k_bcount<<<NBLK1, 256, 0, stream>>>(dst, gbcnt);
    k_bscan<<<1, 256, 0, stream>>>(gbcnt, boffB, gcurB);
    k_bscatter<<<NBLK1, 256, 0, stream>>>(src, dst, gcurB, ebpack);
    k_bbuild<<<NBUCK, 256, 0, stream>>>(ebpack, boffB, offs, esrc);

    k_egemm<<<NPAD / 32, 256, 0, stream>>>(h, wsw, bemb, xb, xq);

    for (int l = 0; l < N_LAYERSC; l++) {
        k_aggregate<<<(N_NODESC * 32 + 255) / 256, 256, 0, stream>>>(xq, offs, esrc, cq);
        k_lgemm<<<NPAD / 32, 256, 0, stream>>>(
            xb, cq,
            wsw + IN_DIMC * HIDC + (size_t)l * 2 * HIDC * HIDC,
            bs + (size_t)l * HIDC, xq);
    }
    k_pool<<<N_GRAPHSC * 4, 256, 0, stream>>>(xb, gstart, hg);
    k_readout<<<N_GRAPHSC, 256, 0, stream>>>(hg, ppos, pneg, wfc, out);
}

// Round 16
// 426.397 us; speedup vs baseline: 1.2346x; 1.0309x over previous
//
#include <hip/hip_runtime.h>
#include <math.h>

#define N_NODESC 50000
#define NPAD 50048              // 1564 * 32
#define N_EDGESC 800000
#define N_GRAPHSC 64
#define IN_DIMC 128
#define HIDC 256
#define N_LAYERSC 4
#define EPSV 1e-12f

#define NBUCK 196               // buckets of 256 nodes
#define EPB 4096
#define NBLK1 196               // ceil(800000/4096)

typedef __attribute__((ext_vector_type(8))) short short8;
typedef __attribute__((ext_vector_type(4))) float floatx4;
typedef __attribute__((ext_vector_type(2))) float floatx2;

__device__ __forceinline__ unsigned short f2b(float f) {
    union { float f; unsigned u; } v; v.f = f;
    unsigned r = v.u + 0x7FFFu + ((v.u >> 16) & 1u);
    return (unsigned short)(r >> 16);
}
__device__ __forceinline__ float blo(unsigned u) { return __uint_as_float(u << 16); }
__device__ __forceinline__ float bhi(unsigned u) { return __uint_as_float(u & 0xFFFF0000u); }
__device__ __forceinline__ unsigned pkb(float a, float b) {
    return (unsigned)f2b(a) | ((unsigned)f2b(b) << 16);
}
__device__ __forceinline__ float b2f(unsigned short s) {
    return __uint_as_float((unsigned)s << 16);
}
__device__ __forceinline__ unsigned char f2q(float v) {
    return (unsigned char)(__builtin_amdgcn_cvt_pk_fp8_f32(v, v, 0, false) & 0xFF);
}
__device__ __forceinline__ unsigned pk4q(float a, float b, float c, float d) {
    unsigned lo = (unsigned)__builtin_amdgcn_cvt_pk_fp8_f32(a, b, 0, false) & 0xFFFFu;
    unsigned hi = (unsigned)__builtin_amdgcn_cvt_pk_fp8_f32(c, d, 0, false) << 16;
    return lo | hi;
}
__device__ __forceinline__ void ldscp16(const void* g, void* l) {
    __builtin_amdgcn_global_load_lds(
        (const __attribute__((address_space(1))) unsigned int*)g,
        (__attribute__((address_space(3))) unsigned int*)l, 16, 0, 0);
}

// ---------------- graph boundaries via binary search (gid sorted) ----------------
__global__ __launch_bounds__(128) void k_gbounds(const int* __restrict__ gid,
        int* __restrict__ gstart) {
    int g = threadIdx.x;
    if (g > N_GRAPHSC) return;
    int lo = 0, hi = N_NODESC;
    while (lo < hi) {
        int mid = (lo + hi) >> 1;
        if (gid[mid] < g) lo = mid + 1; else hi = mid;
    }
    gstart[g] = lo;
}

// ---------------- CSR build, bucketed (bucket = dst>>8) ----------------
__global__ __launch_bounds__(256) void k_bcount(const int* __restrict__ dst,
        int* __restrict__ gbcnt) {
    __shared__ int bc[256];
    int t = threadIdx.x;
    bc[t] = 0;
    __syncthreads();
    int e0 = blockIdx.x * EPB;
    for (int i = t; i < EPB; i += 256) {
        int e = e0 + i;
        if (e < N_EDGESC) atomicAdd(&bc[dst[e] >> 8], 1);
    }
    __syncthreads();
    if (t < NBUCK && bc[t] > 0) atomicAdd(&gbcnt[t], bc[t]);
}

__global__ __launch_bounds__(256) void k_bscan(const int* __restrict__ gbcnt,
        int* __restrict__ boffB, int* __restrict__ gcurB) {
    __shared__ int s[256];
    int t = threadIdx.x;
    int v = (t < NBUCK) ? gbcnt[t] : 0;
    s[t] = v;
    __syncthreads();
    for (int d = 1; d < 256; d <<= 1) {
        int u = (t >= d) ? s[t - d] : 0;
        __syncthreads();
        s[t] += u;
        __syncthreads();
    }
    if (t < NBUCK) {
        int excl = s[t] - v;
        boffB[t] = excl;
        gcurB[t] = excl;
    }
    if (t == 0) boffB[NBUCK] = N_EDGESC;
}

__global__ __launch_bounds__(256) void k_bscatter(const int* __restrict__ src,
        const int* __restrict__ dst, int* __restrict__ gcurB,
        unsigned* __restrict__ ebpack) {
    __shared__ int bc[256];
    __shared__ int cur[256];
    int t = threadIdx.x;
    bc[t] = 0;
    __syncthreads();
    int e0 = blockIdx.x * EPB;
    for (int i = t; i < EPB; i += 256) {
        int e = e0 + i;
        if (e < N_EDGESC) atomicAdd(&bc[dst[e] >> 8], 1);
    }
    __syncthreads();
    if (t < NBUCK)
        cur[t] = (bc[t] > 0) ? atomicAdd(&gcurB[t], bc[t]) : 0;
    __syncthreads();
    for (int i = t; i < EPB; i += 256) {
        int e = e0 + i;
        if (e < N_EDGESC) {
            int d = dst[e];
            int b = d >> 8;
            int pos = atomicAdd(&cur[b], 1);
            ebpack[pos] = (unsigned)src[e] | ((unsigned)(d & 255) << 16);
        }
    }
}

__global__ __launch_bounds__(256) void k_bbuild(const unsigned* __restrict__ ebpack,
        const int* __restrict__ boffB, int* __restrict__ offs,
        unsigned short* __restrict__ esrc) {
    __shared__ int deg[256];
    __shared__ int lofs[256];
    __shared__ unsigned short img[12288];
    int b = blockIdx.x;
    int t = threadIdx.x;
    int bbase = boffB[b];
    int cnt = boffB[b + 1] - bbase;
    deg[t] = 0;
    __syncthreads();
    for (int i = t; i < cnt; i += 256)
        atomicAdd(&deg[ebpack[bbase + i] >> 16], 1);
    __syncthreads();
    int v = deg[t];
    lofs[t] = v;
    __syncthreads();
    for (int d = 1; d < 256; d <<= 1) {
        int u = (t >= d) ? lofs[t - d] : 0;
        __syncthreads();
        lofs[t] += u;
        __syncthreads();
    }
    int excl = lofs[t] - v;
    int node = b * 256 + t;
    if (node < N_NODESC) offs[node] = bbase + excl;
    if (b == NBUCK - 1 && t == 0) offs[N_NODESC] = N_EDGESC;
    deg[t] = excl;
    __syncthreads();
    for (int i = t; i < cnt; i += 256) {
        unsigned p = ebpack[bbase + i];
        int pos = atomicAdd(&deg[p >> 16], 1);
        img[pos] = (unsigned short)(p & 0xFFFF);
    }
    __syncthreads();
    for (int i = t; i < cnt; i += 256)
        esrc[bbase + i] = img[i];
}

// ---------------- weight convert: embed -> bf16 frags; layers -> fp8 frags ----------------
__global__ __launch_bounds__(256) void k_wconv(const float* __restrict__ Wemb,
        const float* __restrict__ Ws, unsigned short* __restrict__ wsw,
        unsigned char* __restrict__ wq) {
    int idx = blockIdx.x * 256 + threadIdx.x;
    const int EMB = IN_DIMC * HIDC;           // 32768
    const int LYR = 2 * HIDC * HIDC;          // 131072
    if (idx >= EMB + N_LAYERSC * LYR) return;
    if (idx < EMB) {
        int k = idx >> 8, n = idx & 255;
        int off = (((k >> 5) * 16 + (n >> 4)) * 64 + ((((k >> 3) & 3) << 4) | (n & 15))) * 8 + (k & 7);
        wsw[off] = f2b(Wemb[idx]);
    } else {
        int r = idx - EMB;
        int l = r >> 17;
        int r2 = r & (LYR - 1);
        int k = r2 >> 8, n = r2 & 255;
        int off = (((k >> 5) * 16 + (n >> 4)) * 64 + ((((k >> 3) & 3) << 4) | (n & 15))) * 8 + (k & 7);
        wq[(size_t)l * LYR + off] = f2q(Ws[r]);
    }
}

// ---------------- per-node mean aggregation: fp8 gather -> fp8 output ----------------
__global__ __launch_bounds__(256) void k_aggregate(const unsigned char* __restrict__ xq,
        const int* __restrict__ offs, const unsigned short* __restrict__ esrc,
        unsigned char* __restrict__ cq) {
    int gidx = blockIdx.x * 256 + threadIdx.x;
    int node = gidx >> 5;
    int lane = threadIdx.x & 31;
    if (node >= N_NODESC) return;
    int beg = offs[node], end = offs[node + 1];
    float a[8];
    #pragma unroll
    for (int j = 0; j < 8; j++) a[j] = 0.f;
    size_t loff = (size_t)lane * 8;
    int e = beg;
    #define ACC8(v) do { \
        floatx2 t0 = __builtin_amdgcn_cvt_pk_f32_fp8((v).x, false); \
        floatx2 t1 = __builtin_amdgcn_cvt_pk_f32_fp8((v).x, true);  \
        floatx2 t2 = __builtin_amdgcn_cvt_pk_f32_fp8((v).y, false); \
        floatx2 t3 = __builtin_amdgcn_cvt_pk_f32_fp8((v).y, true);  \
        a[0] += t0.x; a[1] += t0.y; a[2] += t1.x; a[3] += t1.y;     \
        a[4] += t2.x; a[5] += t2.y; a[6] += t3.x; a[7] += t3.y;     \
    } while (0)
    for (; e + 8 <= end; e += 8) {
        int sidx[8];
        #pragma unroll
        for (int j = 0; j < 8; j++) sidx[j] = esrc[e + j];
        uint2 v[8];
        #pragma unroll
        for (int j = 0; j < 8; j++)
            v[j] = *(const uint2*)(xq + (size_t)sidx[j] * HIDC + loff);
        #pragma unroll
        for (int j = 0; j < 8; j++) ACC8(v[j]);
    }
    if (e + 4 <= end) {
        int sidx[4];
        #pragma unroll
        for (int j = 0; j < 4; j++) sidx[j] = esrc[e + j];
        uint2 v[4];
        #pragma unroll
        for (int j = 0; j < 4; j++)
            v[j] = *(const uint2*)(xq + (size_t)sidx[j] * HIDC + loff);
        #pragma unroll
        for (int j = 0; j < 4; j++) ACC8(v[j]);
        e += 4;
    }
    for (; e < end; e++) {
        uint2 v = *(const uint2*)(xq + (size_t)esrc[e] * HIDC + loff);
        ACC8(v);
    }
    #undef ACC8
    float w = 1.0f / (float)max(end - beg, 1);
    uint2 o;
    o.x = pk4q(a[0] * w, a[1] * w, a[2] * w, a[3] * w);
    o.y = pk4q(a[4] * w, a[5] * w, a[6] * w, a[7] * w);
    *(uint2*)(cq + (size_t)node * HIDC + loff) = o;
}

// ---------------- layer GEMM: fp8 MFMA, dual 8KB async fp8 panels, single barrier ----------------
// panelA <- xq own rows, panelC <- cq own rows (both async global_load_lds, XOR-swizzled
// 16B chunks). 16 K-steps of v_mfma_f32_16x16x32_fp8_fp8 with fp8 B frags (wq, L2-hot).
// Epilogue: bias, row L2-norm, relu, residual (bf16 xb) -> xb + xq (in-place own rows).
__global__ __launch_bounds__(256, 6) void k_lgemm(unsigned short* __restrict__ xb,
        unsigned char* __restrict__ xq, const unsigned char* __restrict__ cq,
        const unsigned char* __restrict__ wq, const float* __restrict__ bias) {
    __shared__ unsigned long long panelA64[1024];  // 8 KB
    __shared__ unsigned long long panelC64[1024];  // 8 KB
    __shared__ float rs[32];
    unsigned char* panelA = (unsigned char*)panelA64;
    unsigned char* panelC = (unsigned char*)panelC64;
    int tid = threadIdx.x;
    int w = tid >> 6;
    int lane = tid & 63;
    int quad = lane >> 4;
    int l15 = lane & 15;
    int row0 = blockIdx.x * 32;

    // async stage both fp8 panels (wave w covers bytes [w*2048, w*2048+2048) of each)
    {
        int sboff = w * 2048 + lane * 16;
        #pragma unroll
        for (int i = 0; i < 2; i++) {
            int ldsoff = sboff + i * 1024;
            int r = ldsoff >> 8;                  // row 0..31 (256 B/row)
            int ch = (ldsoff & 255) >> 4;         // physical 16B chunk 0..15
            int lc = ch ^ (r & 15);               // logical chunk (XOR swizzle)
            ldscp16(xq + (size_t)(row0 + r) * HIDC + lc * 16, &panelA[w * 2048 + i * 1024]);
            ldscp16(cq + (size_t)(row0 + r) * HIDC + lc * 16, &panelC[w * 2048 + i * 1024]);
        }
    }
    __syncthreads();   // vmcnt drained -> both panels visible

    floatx4 acc[2][4];
    #pragma unroll
    for (int mt = 0; mt < 2; mt++)
        #pragma unroll
        for (int n = 0; n < 4; n++)
            acc[mt][n] = (floatx4){0.f, 0.f, 0.f, 0.f};

    const unsigned char* bp = wq + ((size_t)(w * 4) * 64 + lane) * 8;  // bytes; step stride 8192

    #pragma unroll
    for (int st = 0; st < 16; st++) {
        const unsigned char* pan = (st < 8) ? panelA : panelC;
        int ks = st & 7;
        long long afr[2], bfr[4];
        #pragma unroll
        for (int mt = 0; mt < 2; mt++) {
            int row = mt * 16 + l15;
            int lc = ks * 2 + (quad >> 1);        // logical 16B chunk of this frag
            int phys = lc ^ (row & 15);
            afr[mt] = *(const long long*)&pan[row * 256 + phys * 16 + (quad & 1) * 8];
        }
        const unsigned char* wp = bp + (size_t)st * 8192;
        #pragma unroll
        for (int n = 0; n < 4; n++)
            bfr[n] = *(const long long*)(wp + n * 512);
        #pragma unroll
        for (int mt = 0; mt < 2; mt++)
            #pragma unroll
            for (int n = 0; n < 4; n++)
                acc[mt][n] = __builtin_amdgcn_mfma_f32_16x16x32_fp8_fp8(
                    afr[mt], bfr[n], acc[mt][n], 0, 0, 0);
    }

    float bv[4];
    #pragma unroll
    for (int n = 0; n < 4; n++) bv[n] = bias[w * 64 + n * 16 + l15];
    #pragma unroll
    for (int mt = 0; mt < 2; mt++)
        #pragma unroll
        for (int n = 0; n < 4; n++)
            #pragma unroll
            for (int r = 0; r < 4; r++)
                acc[mt][n][r] += bv[n];

    // row L2-norm across 4 col-waves
    __syncthreads();
    if (tid < 32) rs[tid] = 0.f;
    __syncthreads();
    #pragma unroll
    for (int mt = 0; mt < 2; mt++) {
        #pragma unroll
        for (int r = 0; r < 4; r++) {
            float p = acc[mt][0][r] * acc[mt][0][r] + acc[mt][1][r] * acc[mt][1][r]
                    + acc[mt][2][r] * acc[mt][2][r] + acc[mt][3][r] * acc[mt][3][r];
            p += __shfl_xor(p, 1);
            p += __shfl_xor(p, 2);
            p += __shfl_xor(p, 4);
            p += __shfl_xor(p, 8);
            if (l15 == 0) atomicAdd(&rs[mt * 16 + quad * 4 + r], p);
        }
    }
    __syncthreads();

    #pragma unroll
    for (int mt = 0; mt < 2; mt++) {
        #pragma unroll
        for (int r = 0; r < 4; r++) {
            int row = row0 + mt * 16 + quad * 4 + r;
            if (row < N_NODESC) {
                float inv = 1.0f / fmaxf(sqrtf(rs[mt * 16 + quad * 4 + r]), EPSV);
                #pragma unroll
                for (int n = 0; n < 4; n++) {
                    int col = w * 64 + n * 16 + l15;
                    size_t idx = (size_t)row * HIDC + col;
                    float xo = b2f(xb[idx]);
                    float v = fmaxf(acc[mt][n][r] * inv, 0.f);
                    float nv = xo + v;
                    xb[idx] = f2b(nv);
                    xq[idx] = f2q(nv);
                }
            }
        }
    }
}

// ---------------- embed GEMM: 32-row blocks, direct fp32 frag loads (bf16 MFMA) ----------------
__global__ __launch_bounds__(256, 4) void k_egemm(const float* __restrict__ h,
        const unsigned short* __restrict__ wsw, const float* __restrict__ bias,
        unsigned short* __restrict__ xb, unsigned char* __restrict__ xq) {
    int tid = threadIdx.x;
    int wn = tid >> 6;
    int lane = tid & 63;
    int quad = lane >> 4;
    int l15 = lane & 15;
    int row0 = blockIdx.x * 32;

    floatx4 acc[2][4];
    #pragma unroll
    for (int mt = 0; mt < 2; mt++)
        #pragma unroll
        for (int n = 0; n < 4; n++)
            acc[mt][n] = (floatx4){0.f, 0.f, 0.f, 0.f};

    int r0 = row0 + l15;
    int r1 = row0 + 16 + l15;
    bool ok0 = r0 < N_NODESC, ok1 = r1 < N_NODESC;
    const float* h0 = h + (size_t)r0 * IN_DIMC + quad * 8;
    const float* h1 = h + (size_t)r1 * IN_DIMC + quad * 8;
    const unsigned short* bp = wsw + ((size_t)(wn * 4) * 64 + lane) * 8;

    #pragma unroll
    for (int ks = 0; ks < 4; ks++) {
        float4 f00 = ok0 ? *(const float4*)(h0 + ks * 32)     : (float4){0,0,0,0};
        float4 f01 = ok0 ? *(const float4*)(h0 + ks * 32 + 4) : (float4){0,0,0,0};
        float4 f10 = ok1 ? *(const float4*)(h1 + ks * 32)     : (float4){0,0,0,0};
        float4 f11 = ok1 ? *(const float4*)(h1 + ks * 32 + 4) : (float4){0,0,0,0};
        short8 afr[2], bfr[4];
        uint4 av;
        av.x = pkb(f00.x, f00.y); av.y = pkb(f00.z, f00.w);
        av.z = pkb(f01.x, f01.y); av.w = pkb(f01.z, f01.w);
        afr[0] = *(short8*)&av;
        av.x = pkb(f10.x, f10.y); av.y = pkb(f10.z, f10.w);
        av.z = pkb(f11.x, f11.y); av.w = pkb(f11.z, f11.w);
        afr[1] = *(short8*)&av;
        const unsigned short* wp = bp + (size_t)ks * 8192;
        #pragma unroll
        for (int n = 0; n < 4; n++)
            bfr[n] = *(const short8*)(wp + n * 512);
        #pragma unroll
        for (int mt = 0; mt < 2; mt++)
            #pragma unroll
            for (int n = 0; n < 4; n++)
                acc[mt][n] = __builtin_amdgcn_mfma_f32_16x16x32_bf16(
                    afr[mt], bfr[n], acc[mt][n], 0, 0, 0);
    }

    float bv[4];
    #pragma unroll
    for (int n = 0; n < 4; n++) bv[n] = bias[wn * 64 + n * 16 + l15];
    #pragma unroll
    for (int mt = 0; mt < 2; mt++) {
        #pragma unroll
        for (int r = 0; r < 4; r++) {
            int row = row0 + mt * 16 + quad * 4 + r;
            if (row < N_NODESC) {
                #pragma unroll
                for (int n = 0; n < 4; n++) {
                    int col = wn * 64 + n * 16 + l15;
                    float v = acc[mt][n][r] + bv[n];
                    size_t idx = (size_t)row * HIDC + col;
                    xb[idx] = f2b(v);
                    xq[idx] = f2q(v);
                }
            }
        }
    }
}

// ---------------- graph mean-pool: 1 block per (graph, 64-col quarter) ----------------
__global__ __launch_bounds__(256) void k_pool(const unsigned short* __restrict__ xb,
        const int* __restrict__ gstart, float* __restrict__ hg) {
    __shared__ float red[256][8];
    int g = blockIdx.x >> 2;
    int cq = blockIdx.x & 3;
    int t = threadIdx.x;
    int cchunk = t & 7;
    int rgrp = t >> 3;
    int col0 = cq * 64 + cchunk * 8;
    int beg = gstart[g], end = gstart[g + 1];
    float a[8];
    #pragma unroll
    for (int j = 0; j < 8; j++) a[j] = 0.f;
    for (int r = beg + rgrp; r < end; r += 32) {
        uint4 v = *(const uint4*)(xb + (size_t)r * HIDC + col0);
        a[0] += blo(v.x); a[1] += bhi(v.x);
        a[2] += blo(v.y); a[3] += bhi(v.y);
        a[4] += blo(v.z); a[5] += bhi(v.z);
        a[6] += blo(v.w); a[7] += bhi(v.w);
    }
    #pragma unroll
    for (int j = 0; j < 8; j++) red[t][j] = a[j];
    __syncthreads();
    for (int d = 16; d >= 1; d >>= 1) {
        if (rgrp < d) {
            #pragma unroll
            for (int j = 0; j < 8; j++) red[t][j] += red[t + d * 8][j];
        }
        __syncthreads();
    }
    if (rgrp == 0) {
        float inv = 1.0f / (float)max(end - beg, 1);
        #pragma unroll
        for (int j = 0; j < 8; j++)
            hg[g * HIDC + col0 + j] = red[t][j] * inv;
    }
}

// ---------------- readout ----------------
__global__ __launch_bounds__(256) void k_readout(const float* __restrict__ hg,
        const float* __restrict__ ppos, const float* __restrict__ pneg,
        const float* __restrict__ wfc, float* __restrict__ out) {
    __shared__ float red[256];
    __shared__ float ss[10];
    int t = threadIdx.x;
    int g = blockIdx.x;
    float hgv = hg[g * HIDC + t];
    for (int p = 0; p < 10; p++) {
        const float* P = (p < 5) ? (ppos + p * HIDC) : (pneg + (p - 5) * HIDC);
        float d = hgv - P[t];
        red[t] = d * d;
        __syncthreads();
        for (int s2 = 128; s2 > 0; s2 >>= 1) {
            if (t < s2) red[t] += red[t + s2];
            __syncthreads();
        }
        if (t == 0) {
            float dd = red[0];
            ss[p] = logf((dd + 1.0f) / (dd + EPSV));
        }
        __syncthreads();
    }
    if (t == 0) {
        float y = 0.f;
        #pragma unroll
        for (int p = 0; p < 10; p++) y += ss[p] * wfc[p];
        out[g] = 1.0f / (1.0f + expf(-y));
    }
}

extern "C" void kernel_launch(void* const* d_in, const int* in_sizes, int n_in,
                              void* d_out, int out_size, void* d_ws, size_t ws_size,
                              hipStream_t stream) {
    const float* h    = (const float*)d_in[0];
    const int*   src  = (const int*)d_in[1];
    const int*   dst  = (const int*)d_in[2];
    const int*   gid  = (const int*)d_in[3];
    const float* Wemb = (const float*)d_in[4];
    const float* bemb = (const float*)d_in[5];
    const float* Ws   = (const float*)d_in[6];
    const float* bs   = (const float*)d_in[7];
    const float* ppos = (const float*)d_in[8];
    const float* pneg = (const float*)d_in[9];
    const float* wfc  = (const float*)d_in[10];
    float* out = (float*)d_out;

    char* ws = (char*)d_ws;
    size_t off = 0;
    auto alloc = [&](size_t bytes) {
        void* p = ws + off;
        off += (bytes + 255) & ~(size_t)255;
        return p;
    };
    unsigned short* xb     = (unsigned short*)alloc((size_t)NPAD * HIDC * 2);  // bf16 row-major
    unsigned char*  xq     = (unsigned char*)alloc((size_t)NPAD * HIDC);       // fp8 shadow
    unsigned char*  cq     = (unsigned char*)alloc((size_t)NPAD * HIDC);       // fp8 aggregate out
    unsigned short* wsw    = (unsigned short*)alloc((size_t)(IN_DIMC * HIDC) * 2);          // bf16 embed W
    unsigned char*  wq     = (unsigned char*)alloc((size_t)(N_LAYERSC * 2 * HIDC * HIDC)); // fp8 layer W
    int*            offs   = (int*)alloc((size_t)(N_NODESC + 1) * 4);
    unsigned short* esrc   = (unsigned short*)alloc((size_t)N_EDGESC * 2);
    unsigned*       ebpack = (unsigned*)alloc((size_t)N_EDGESC * 4);
    int*            gbcnt  = (int*)alloc((size_t)NBUCK * 4);
    int*            boffB  = (int*)alloc((size_t)(NBUCK + 1) * 4);
    int*            gcurB  = (int*)alloc((size_t)NBUCK * 4);
    int*            gstart = (int*)alloc((size_t)(N_GRAPHSC + 1) * 4);
    float*          hg     = (float*)alloc((size_t)N_GRAPHSC * HIDC * 4);
    (void)ws_size; (void)in_sizes; (void)n_in; (void)out_size;

    hipMemsetAsync(gbcnt, 0, (size_t)NBUCK * 4, stream);

    const int WTOT = IN_DIMC * HIDC + N_LAYERSC * 2 * HIDC * HIDC; // 557056
    k_wconv<<<(WTOT + 255) / 256, 256, 0, stream>>>(Wemb, Ws, wsw, wq);
    k_gbounds<<<1, 128, 0, stream>>>(gid, gstart);
    k_bcount<<<NBLK1, 256, 0, stream>>>(dst, gbcnt);
    k_bscan<<<1, 256, 0, stream>>>(gbcnt, boffB, gcurB);
    k_bscatter<<<NBLK1, 256, 0, stream>>>(src, dst, gcurB, ebpack);
    k_bbuild<<<NBUCK, 256, 0, stream>>>(ebpack, boffB, offs, esrc);

    k_egemm<<<NPAD / 32, 256, 0, stream>>>(h, wsw, bemb, xb, xq);

    for (int l = 0; l < N_LAYERSC; l++) {
        k_aggregate<<<(N_NODESC * 32 + 255) / 256, 256, 0, stream>>>(xq, offs, esrc, cq);
        k_lgemm<<<NPAD / 32, 256, 0, stream>>>(
            xb, xq, cq,
            wq + (size_t)l * 2 * HIDC * HIDC,
            bs + (size_t)l * HIDC);
    }
    k_pool<<<N_GRAPHSC * 4, 256, 0, stream>>>(xb, gstart, hg);
    k_readout<<<N_GRAPHSC, 256, 0, stream>>>(hg, ppos, pneg, wfc, out);
}

// Round 17
// 392.392 us; speedup vs baseline: 1.3416x; 1.0867x over previous
//
#include <hip/hip_runtime.h>
#include <math.h>

#define N_NODESC 50000
#define NPAD 50048              // 1564 * 32
#define N_EDGESC 800000
#define N_GRAPHSC 64
#define IN_DIMC 128
#define HIDC 256
#define N_LAYERSC 4
#define EPSV 1e-12f

#define NBUCK 196               // buckets of 256 nodes
#define EPB 4096
#define NBLK1 196               // ceil(800000/4096)

typedef __attribute__((ext_vector_type(8))) short short8;
typedef __attribute__((ext_vector_type(4))) float floatx4;
typedef __attribute__((ext_vector_type(2))) float floatx2;

__device__ __forceinline__ unsigned short f2b(float f) {
    union { float f; unsigned u; } v; v.f = f;
    unsigned r = v.u + 0x7FFFu + ((v.u >> 16) & 1u);
    return (unsigned short)(r >> 16);
}
__device__ __forceinline__ float blo(unsigned u) { return __uint_as_float(u << 16); }
__device__ __forceinline__ float bhi(unsigned u) { return __uint_as_float(u & 0xFFFF0000u); }
__device__ __forceinline__ unsigned pkb(float a, float b) {
    return (unsigned)f2b(a) | ((unsigned)f2b(b) << 16);
}
__device__ __forceinline__ float b2f(unsigned short s) {
    return __uint_as_float((unsigned)s << 16);
}
__device__ __forceinline__ unsigned char f2q(float v) {
    return (unsigned char)(__builtin_amdgcn_cvt_pk_fp8_f32(v, v, 0, false) & 0xFF);
}
__device__ __forceinline__ float q2f(unsigned u) {
    floatx2 t = __builtin_amdgcn_cvt_pk_f32_fp8(u, false);
    return t.x;   // converts byte 0
}
__device__ __forceinline__ unsigned pk4q(float a, float b, float c, float d) {
    unsigned lo = (unsigned)__builtin_amdgcn_cvt_pk_fp8_f32(a, b, 0, false) & 0xFFFFu;
    unsigned hi = (unsigned)__builtin_amdgcn_cvt_pk_fp8_f32(c, d, 0, false) << 16;
    return lo | hi;
}
__device__ __forceinline__ void ldscp16(const void* g, void* l) {
    __builtin_amdgcn_global_load_lds(
        (const __attribute__((address_space(1))) unsigned int*)g,
        (__attribute__((address_space(3))) unsigned int*)l, 16, 0, 0);
}

// ---------------- graph boundaries via binary search (gid sorted) ----------------
__global__ __launch_bounds__(128) void k_gbounds(const int* __restrict__ gid,
        int* __restrict__ gstart) {
    int g = threadIdx.x;
    if (g > N_GRAPHSC) return;
    int lo = 0, hi = N_NODESC;
    while (lo < hi) {
        int mid = (lo + hi) >> 1;
        if (gid[mid] < g) lo = mid + 1; else hi = mid;
    }
    gstart[g] = lo;
}

// ---------------- CSR build, bucketed (bucket = dst>>8) ----------------
__global__ __launch_bounds__(256) void k_bcount(const int* __restrict__ dst,
        int* __restrict__ gbcnt) {
    __shared__ int bc[256];
    int t = threadIdx.x;
    bc[t] = 0;
    __syncthreads();
    int e0 = blockIdx.x * EPB;
    for (int i = t; i < EPB; i += 256) {
        int e = e0 + i;
        if (e < N_EDGESC) atomicAdd(&bc[dst[e] >> 8], 1);
    }
    __syncthreads();
    if (t < NBUCK && bc[t] > 0) atomicAdd(&gbcnt[t], bc[t]);
}

__global__ __launch_bounds__(256) void k_bscan(const int* __restrict__ gbcnt,
        int* __restrict__ boffB, int* __restrict__ gcurB) {
    __shared__ int s[256];
    int t = threadIdx.x;
    int v = (t < NBUCK) ? gbcnt[t] : 0;
    s[t] = v;
    __syncthreads();
    for (int d = 1; d < 256; d <<= 1) {
        int u = (t >= d) ? s[t - d] : 0;
        __syncthreads();
        s[t] += u;
        __syncthreads();
    }
    if (t < NBUCK) {
        int excl = s[t] - v;
        boffB[t] = excl;
        gcurB[t] = excl;
    }
    if (t == 0) boffB[NBUCK] = N_EDGESC;
}

__global__ __launch_bounds__(256) void k_bscatter(const int* __restrict__ src,
        const int* __restrict__ dst, int* __restrict__ gcurB,
        unsigned* __restrict__ ebpack) {
    __shared__ int bc[256];
    __shared__ int cur[256];
    int t = threadIdx.x;
    bc[t] = 0;
    __syncthreads();
    int e0 = blockIdx.x * EPB;
    for (int i = t; i < EPB; i += 256) {
        int e = e0 + i;
        if (e < N_EDGESC) atomicAdd(&bc[dst[e] >> 8], 1);
    }
    __syncthreads();
    if (t < NBUCK)
        cur[t] = (bc[t] > 0) ? atomicAdd(&gcurB[t], bc[t]) : 0;
    __syncthreads();
    for (int i = t; i < EPB; i += 256) {
        int e = e0 + i;
        if (e < N_EDGESC) {
            int d = dst[e];
            int b = d >> 8;
            int pos = atomicAdd(&cur[b], 1);
            ebpack[pos] = (unsigned)src[e] | ((unsigned)(d & 255) << 16);
        }
    }
}

__global__ __launch_bounds__(256) void k_bbuild(const unsigned* __restrict__ ebpack,
        const int* __restrict__ boffB, int* __restrict__ offs,
        unsigned short* __restrict__ esrc) {
    __shared__ int deg[256];
    __shared__ int lofs[256];
    __shared__ unsigned short img[12288];
    int b = blockIdx.x;
    int t = threadIdx.x;
    int bbase = boffB[b];
    int cnt = boffB[b + 1] - bbase;
    deg[t] = 0;
    __syncthreads();
    for (int i = t; i < cnt; i += 256)
        atomicAdd(&deg[ebpack[bbase + i] >> 16], 1);
    __syncthreads();
    int v = deg[t];
    lofs[t] = v;
    __syncthreads();
    for (int d = 1; d < 256; d <<= 1) {
        int u = (t >= d) ? lofs[t - d] : 0;
        __syncthreads();
        lofs[t] += u;
        __syncthreads();
    }
    int excl = lofs[t] - v;
    int node = b * 256 + t;
    if (node < N_NODESC) offs[node] = bbase + excl;
    if (b == NBUCK - 1 && t == 0) offs[N_NODESC] = N_EDGESC;
    deg[t] = excl;
    __syncthreads();
    for (int i = t; i < cnt; i += 256) {
        unsigned p = ebpack[bbase + i];
        int pos = atomicAdd(&deg[p >> 16], 1);
        img[pos] = (unsigned short)(p & 0xFFFF);
    }
    __syncthreads();
    for (int i = t; i < cnt; i += 256)
        esrc[bbase + i] = img[i];
}

// ---------------- weight convert: embed -> bf16 frags; layers -> fp8 frags ----------------
__global__ __launch_bounds__(256) void k_wconv(const float* __restrict__ Wemb,
        const float* __restrict__ Ws, unsigned short* __restrict__ wsw,
        unsigned char* __restrict__ wq) {
    int idx = blockIdx.x * 256 + threadIdx.x;
    const int EMB = IN_DIMC * HIDC;           // 32768
    const int LYR = 2 * HIDC * HIDC;          // 131072
    if (idx >= EMB + N_LAYERSC * LYR) return;
    if (idx < EMB) {
        int k = idx >> 8, n = idx & 255;
        int off = (((k >> 5) * 16 + (n >> 4)) * 64 + ((((k >> 3) & 3) << 4) | (n & 15))) * 8 + (k & 7);
        wsw[off] = f2b(Wemb[idx]);
    } else {
        int r = idx - EMB;
        int l = r >> 17;
        int r2 = r & (LYR - 1);
        int k = r2 >> 8, n = r2 & 255;
        int off = (((k >> 5) * 16 + (n >> 4)) * 64 + ((((k >> 3) & 3) << 4) | (n & 15))) * 8 + (k & 7);
        wq[(size_t)l * LYR + off] = f2q(Ws[r]);
    }
}

// ---------------- per-node mean aggregation: fp8 gather -> fp8 output ----------------
__global__ __launch_bounds__(256) void k_aggregate(const unsigned char* __restrict__ xq,
        const int* __restrict__ offs, const unsigned short* __restrict__ esrc,
        unsigned char* __restrict__ cq) {
    int gidx = blockIdx.x * 256 + threadIdx.x;
    int node = gidx >> 5;
    int lane = threadIdx.x & 31;
    if (node >= N_NODESC) return;
    int beg = offs[node], end = offs[node + 1];
    float a[8];
    #pragma unroll
    for (int j = 0; j < 8; j++) a[j] = 0.f;
    size_t loff = (size_t)lane * 8;
    int e = beg;
    #define ACC8(v) do { \
        floatx2 t0 = __builtin_amdgcn_cvt_pk_f32_fp8((v).x, false); \
        floatx2 t1 = __builtin_amdgcn_cvt_pk_f32_fp8((v).x, true);  \
        floatx2 t2 = __builtin_amdgcn_cvt_pk_f32_fp8((v).y, false); \
        floatx2 t3 = __builtin_amdgcn_cvt_pk_f32_fp8((v).y, true);  \
        a[0] += t0.x; a[1] += t0.y; a[2] += t1.x; a[3] += t1.y;     \
        a[4] += t2.x; a[5] += t2.y; a[6] += t3.x; a[7] += t3.y;     \
    } while (0)
    for (; e + 8 <= end; e += 8) {
        int sidx[8];
        #pragma unroll
        for (int j = 0; j < 8; j++) sidx[j] = esrc[e + j];
        uint2 v[8];
        #pragma unroll
        for (int j = 0; j < 8; j++)
            v[j] = *(const uint2*)(xq + (size_t)sidx[j] * HIDC + loff);
        #pragma unroll
        for (int j = 0; j < 8; j++) ACC8(v[j]);
    }
    if (e + 4 <= end) {
        int sidx[4];
        #pragma unroll
        for (int j = 0; j < 4; j++) sidx[j] = esrc[e + j];
        uint2 v[4];
        #pragma unroll
        for (int j = 0; j < 4; j++)
            v[j] = *(const uint2*)(xq + (size_t)sidx[j] * HIDC + loff);
        #pragma unroll
        for (int j = 0; j < 4; j++) ACC8(v[j]);
        e += 4;
    }
    for (; e < end; e++) {
        uint2 v = *(const uint2*)(xq + (size_t)esrc[e] * HIDC + loff);
        ACC8(v);
    }
    #undef ACC8
    float w = 1.0f / (float)max(end - beg, 1);
    uint2 o;
    o.x = pk4q(a[0] * w, a[1] * w, a[2] * w, a[3] * w);
    o.y = pk4q(a[4] * w, a[5] * w, a[6] * w, a[7] * w);
    *(uint2*)(cq + (size_t)node * HIDC + loff) = o;
}

// ---------------- layer GEMM: fp8 MFMA, dual 8KB async fp8 panels ----------------
// Residual base read from panelA (the same fp8 x the GEMM consumed) -> no xb read.
// LAST=false: write xq only. LAST=true: write xb only (for pooling).
template<bool LAST>
__global__ __launch_bounds__(256, 6) void k_lgemm(unsigned short* __restrict__ xb,
        unsigned char* __restrict__ xq, const unsigned char* __restrict__ cq,
        const unsigned char* __restrict__ wq, const float* __restrict__ bias) {
    __shared__ unsigned long long panelA64[1024];  // 8 KB
    __shared__ unsigned long long panelC64[1024];  // 8 KB
    __shared__ float rs[32];
    unsigned char* panelA = (unsigned char*)panelA64;
    unsigned char* panelC = (unsigned char*)panelC64;
    int tid = threadIdx.x;
    int w = tid >> 6;
    int lane = tid & 63;
    int quad = lane >> 4;
    int l15 = lane & 15;
    int row0 = blockIdx.x * 32;

    // async stage both fp8 panels (wave w covers bytes [w*2048, w*2048+2048) of each)
    {
        int sboff = w * 2048 + lane * 16;
        #pragma unroll
        for (int i = 0; i < 2; i++) {
            int ldsoff = sboff + i * 1024;
            int r = ldsoff >> 8;                  // row 0..31 (256 B/row)
            int ch = (ldsoff & 255) >> 4;         // physical 16B chunk 0..15
            int lc = ch ^ (r & 15);               // logical chunk (XOR swizzle)
            ldscp16(xq + (size_t)(row0 + r) * HIDC + lc * 16, &panelA[w * 2048 + i * 1024]);
            ldscp16(cq + (size_t)(row0 + r) * HIDC + lc * 16, &panelC[w * 2048 + i * 1024]);
        }
    }
    __syncthreads();   // vmcnt drained -> both panels visible

    floatx4 acc[2][4];
    #pragma unroll
    for (int mt = 0; mt < 2; mt++)
        #pragma unroll
        for (int n = 0; n < 4; n++)
            acc[mt][n] = (floatx4){0.f, 0.f, 0.f, 0.f};

    const unsigned char* bp = wq + ((size_t)(w * 4) * 64 + lane) * 8;  // bytes; step stride 8192

    #pragma unroll
    for (int st = 0; st < 16; st++) {
        const unsigned char* pan = (st < 8) ? panelA : panelC;
        int ks = st & 7;
        long long afr[2], bfr[4];
        #pragma unroll
        for (int mt = 0; mt < 2; mt++) {
            int row = mt * 16 + l15;
            int lc = ks * 2 + (quad >> 1);        // logical 16B chunk of this frag
            int phys = lc ^ (row & 15);
            afr[mt] = *(const long long*)&pan[row * 256 + phys * 16 + (quad & 1) * 8];
        }
        const unsigned char* wp = bp + (size_t)st * 8192;
        #pragma unroll
        for (int n = 0; n < 4; n++)
            bfr[n] = *(const long long*)(wp + n * 512);
        #pragma unroll
        for (int mt = 0; mt < 2; mt++)
            #pragma unroll
            for (int n = 0; n < 4; n++)
                acc[mt][n] = __builtin_amdgcn_mfma_f32_16x16x32_fp8_fp8(
                    afr[mt], bfr[n], acc[mt][n], 0, 0, 0);
    }

    float bv[4];
    #pragma unroll
    for (int n = 0; n < 4; n++) bv[n] = bias[w * 64 + n * 16 + l15];
    #pragma unroll
    for (int mt = 0; mt < 2; mt++)
        #pragma unroll
        for (int n = 0; n < 4; n++)
            #pragma unroll
            for (int r = 0; r < 4; r++)
                acc[mt][n][r] += bv[n];

    // row L2-norm across 4 col-waves
    __syncthreads();
    if (tid < 32) rs[tid] = 0.f;
    __syncthreads();
    #pragma unroll
    for (int mt = 0; mt < 2; mt++) {
        #pragma unroll
        for (int r = 0; r < 4; r++) {
            float p = acc[mt][0][r] * acc[mt][0][r] + acc[mt][1][r] * acc[mt][1][r]
                    + acc[mt][2][r] * acc[mt][2][r] + acc[mt][3][r] * acc[mt][3][r];
            p += __shfl_xor(p, 1);
            p += __shfl_xor(p, 2);
            p += __shfl_xor(p, 4);
            p += __shfl_xor(p, 8);
            if (l15 == 0) atomicAdd(&rs[mt * 16 + quad * 4 + r], p);
        }
    }
    __syncthreads();

    #pragma unroll
    for (int mt = 0; mt < 2; mt++) {
        #pragma unroll
        for (int r = 0; r < 4; r++) {
            int lrow = mt * 16 + quad * 4 + r;
            int row = row0 + lrow;
            if (row < N_NODESC) {
                float inv = 1.0f / fmaxf(sqrtf(rs[mt * 16 + quad * 4 + r]), EPSV);
                #pragma unroll
                for (int n = 0; n < 4; n++) {
                    int col = w * 64 + n * 16 + l15;
                    // residual base: fp8 x_old from panelA (same value the GEMM used)
                    int phys = (w * 4 + n) ^ (lrow & 15);
                    float xo = q2f((unsigned)panelA[lrow * 256 + phys * 16 + l15]);
                    float v = fmaxf(acc[mt][n][r] * inv, 0.f);
                    float nv = xo + v;
                    size_t idx = (size_t)row * HIDC + col;
                    if (LAST) xb[idx] = f2b(nv);
                    else      xq[idx] = f2q(nv);
                }
            }
        }
    }
}

// ---------------- embed GEMM: 32-row blocks, direct fp32 frag loads (bf16 MFMA) ----------------
__global__ __launch_bounds__(256, 4) void k_egemm(const float* __restrict__ h,
        const unsigned short* __restrict__ wsw, const float* __restrict__ bias,
        unsigned char* __restrict__ xq) {
    int tid = threadIdx.x;
    int wn = tid >> 6;
    int lane = tid & 63;
    int quad = lane >> 4;
    int l15 = lane & 15;
    int row0 = blockIdx.x * 32;

    floatx4 acc[2][4];
    #pragma unroll
    for (int mt = 0; mt < 2; mt++)
        #pragma unroll
        for (int n = 0; n < 4; n++)
            acc[mt][n] = (floatx4){0.f, 0.f, 0.f, 0.f};

    int r0 = row0 + l15;
    int r1 = row0 + 16 + l15;
    bool ok0 = r0 < N_NODESC, ok1 = r1 < N_NODESC;
    const float* h0 = h + (size_t)r0 * IN_DIMC + quad * 8;
    const float* h1 = h + (size_t)r1 * IN_DIMC + quad * 8;
    const unsigned short* bp = wsw + ((size_t)(wn * 4) * 64 + lane) * 8;

    #pragma unroll
    for (int ks = 0; ks < 4; ks++) {
        float4 f00 = ok0 ? *(const float4*)(h0 + ks * 32)     : (float4){0,0,0,0};
        float4 f01 = ok0 ? *(const float4*)(h0 + ks * 32 + 4) : (float4){0,0,0,0};
        float4 f10 = ok1 ? *(const float4*)(h1 + ks * 32)     : (float4){0,0,0,0};
        float4 f11 = ok1 ? *(const float4*)(h1 + ks * 32 + 4) : (float4){0,0,0,0};
        short8 afr[2], bfr[4];
        uint4 av;
        av.x = pkb(f00.x, f00.y); av.y = pkb(f00.z, f00.w);
        av.z = pkb(f01.x, f01.y); av.w = pkb(f01.z, f01.w);
        afr[0] = *(short8*)&av;
        av.x = pkb(f10.x, f10.y); av.y = pkb(f10.z, f10.w);
        av.z = pkb(f11.x, f11.y); av.w = pkb(f11.z, f11.w);
        afr[1] = *(short8*)&av;
        const unsigned short* wp = bp + (size_t)ks * 8192;
        #pragma unroll
        for (int n = 0; n < 4; n++)
            bfr[n] = *(const short8*)(wp + n * 512);
        #pragma unroll
        for (int mt = 0; mt < 2; mt++)
            #pragma unroll
            for (int n = 0; n < 4; n++)
                acc[mt][n] = __builtin_amdgcn_mfma_f32_16x16x32_bf16(
                    afr[mt], bfr[n], acc[mt][n], 0, 0, 0);
    }

    float bv[4];
    #pragma unroll
    for (int n = 0; n < 4; n++) bv[n] = bias[wn * 64 + n * 16 + l15];
    #pragma unroll
    for (int mt = 0; mt < 2; mt++) {
        #pragma unroll
        for (int r = 0; r < 4; r++) {
            int row = row0 + mt * 16 + quad * 4 + r;
            if (row < N_NODESC) {
                #pragma unroll
                for (int n = 0; n < 4; n++) {
                    int col = wn * 64 + n * 16 + l15;
                    float v = acc[mt][n][r] + bv[n];
                    xq[(size_t)row * HIDC + col] = f2q(v);
                }
            }
        }
    }
}

// ---------------- graph mean-pool: 1 block per (graph, 64-col quarter) ----------------
__global__ __launch_bounds__(256) void k_pool(const unsigned short* __restrict__ xb,
        const int* __restrict__ gstart, float* __restrict__ hg) {
    __shared__ float red[256][8];
    int g = blockIdx.x >> 2;
    int cq = blockIdx.x & 3;
    int t = threadIdx.x;
    int cchunk = t & 7;
    int rgrp = t >> 3;
    int col0 = cq * 64 + cchunk * 8;
    int beg = gstart[g], end = gstart[g + 1];
    float a[8];
    #pragma unroll
    for (int j = 0; j < 8; j++) a[j] = 0.f;
    for (int r = beg + rgrp; r < end; r += 32) {
        uint4 v = *(const uint4*)(xb + (size_t)r * HIDC + col0);
        a[0] += blo(v.x); a[1] += bhi(v.x);
        a[2] += blo(v.y); a[3] += bhi(v.y);
        a[4] += blo(v.z); a[5] += bhi(v.z);
        a[6] += blo(v.w); a[7] += bhi(v.w);
    }
    #pragma unroll
    for (int j = 0; j < 8; j++) red[t][j] = a[j];
    __syncthreads();
    for (int d = 16; d >= 1; d >>= 1) {
        if (rgrp < d) {
            #pragma unroll
            for (int j = 0; j < 8; j++) red[t][j] += red[t + d * 8][j];
        }
        __syncthreads();
    }
    if (rgrp == 0) {
        float inv = 1.0f / (float)max(end - beg, 1);
        #pragma unroll
        for (int j = 0; j < 8; j++)
            hg[g * HIDC + col0 + j] = red[t][j] * inv;
    }
}

// ---------------- readout ----------------
__global__ __launch_bounds__(256) void k_readout(const float* __restrict__ hg,
        const float* __restrict__ ppos, const float* __restrict__ pneg,
        const float* __restrict__ wfc, float* __restrict__ out) {
    __shared__ float red[256];
    __shared__ float ss[10];
    int t = threadIdx.x;
    int g = blockIdx.x;
    float hgv = hg[g * HIDC + t];
    for (int p = 0; p < 10; p++) {
        const float* P = (p < 5) ? (ppos + p * HIDC) : (pneg + (p - 5) * HIDC);
        float d = hgv - P[t];
        red[t] = d * d;
        __syncthreads();
        for (int s2 = 128; s2 > 0; s2 >>= 1) {
            if (t < s2) red[t] += red[t + s2];
            __syncthreads();
        }
        if (t == 0) {
            float dd = red[0];
            ss[p] = logf((dd + 1.0f) / (dd + EPSV));
        }
        __syncthreads();
    }
    if (t == 0) {
        float y = 0.f;
        #pragma unroll
        for (int p = 0; p < 10; p++) y += ss[p] * wfc[p];
        out[g] = 1.0f / (1.0f + expf(-y));
    }
}

extern "C" void kernel_launch(void* const* d_in, const int* in_sizes, int n_in,
                              void* d_out, int out_size, void* d_ws, size_t ws_size,
                              hipStream_t stream) {
    const float* h    = (const float*)d_in[0];
    const int*   src  = (const int*)d_in[1];
    const int*   dst  = (const int*)d_in[2];
    const int*   gid  = (const int*)d_in[3];
    const float* Wemb = (const float*)d_in[4];
    const float* bemb = (const float*)d_in[5];
    const float* Ws   = (const float*)d_in[6];
    const float* bs   = (const float*)d_in[7];
    const float* ppos = (const float*)d_in[8];
    const float* pneg = (const float*)d_in[9];
    const float* wfc  = (const float*)d_in[10];
    float* out = (float*)d_out;

    char* ws = (char*)d_ws;
    size_t off = 0;
    auto alloc = [&](size_t bytes) {
        void* p = ws + off;
        off += (bytes + 255) & ~(size_t)255;
        return p;
    };
    unsigned short* xb     = (unsigned short*)alloc((size_t)NPAD * HIDC * 2);  // bf16, final layer only
    unsigned char*  xq     = (unsigned char*)alloc((size_t)NPAD * HIDC);       // fp8 activation
    unsigned char*  cq     = (unsigned char*)alloc((size_t)NPAD * HIDC);       // fp8 aggregate out
    unsigned short* wsw    = (unsigned short*)alloc((size_t)(IN_DIMC * HIDC) * 2);          // bf16 embed W
    unsigned char*  wq     = (unsigned char*)alloc((size_t)(N_LAYERSC * 2 * HIDC * HIDC)); // fp8 layer W
    int*            offs   = (int*)alloc((size_t)(N_NODESC + 1) * 4);
    unsigned short* esrc   = (unsigned short*)alloc((size_t)N_EDGESC * 2);
    unsigned*       ebpack = (unsigned*)alloc((size_t)N_EDGESC * 4);
    int*            gbcnt  = (int*)alloc((size_t)NBUCK * 4);
    int*            boffB  = (int*)alloc((size_t)(NBUCK + 1) * 4);
    int*            gcurB  = (int*)alloc((size_t)NBUCK * 4);
    int*            gstart = (int*)alloc((size_t)(N_GRAPHSC + 1) * 4);
    float*          hg     = (float*)alloc((size_t)N_GRAPHSC * HIDC * 4);
    (void)ws_size; (void)in_sizes; (void)n_in; (void)out_size;

    hipMemsetAsync(gbcnt, 0, (size_t)NBUCK * 4, stream);

    const int WTOT = IN_DIMC * HIDC + N_LAYERSC * 2 * HIDC * HIDC; // 557056
    k_wconv<<<(WTOT + 255) / 256, 256, 0, stream>>>(Wemb, Ws, wsw, wq);
    k_gbounds<<<1, 128, 0, stream>>>(gid, gstart);
    k_bcount<<<NBLK1, 256, 0, stream>>>(dst, gbcnt);
    k_bscan<<<1, 256, 0, stream>>>(gbcnt, boffB, gcurB);
    k_bscatter<<<NBLK1, 256, 0, stream>>>(src, dst, gcurB, ebpack);
    k_bbuild<<<NBUCK, 256, 0, stream>>>(ebpack, boffB, offs, esrc);

    k_egemm<<<NPAD / 32, 256, 0, stream>>>(h, wsw, bemb, xq);

    for (int l = 0; l < N_LAYERSC; l++) {
        k_aggregate<<<(N_NODESC * 32 + 255) / 256, 256, 0, stream>>>(xq, offs, esrc, cq);
        if (l < N_LAYERSC - 1)
            k_lgemm<false><<<NPAD / 32, 256, 0, stream>>>(
                xb, xq, cq, wq + (size_t)l * 2 * HIDC * HIDC, bs + (size_t)l * HIDC);
        else
            k_lgemm<true><<<NPAD / 32, 256, 0, stream>>>(
                xb, xq, cq, wq + (size_t)l * 2 * HIDC * HIDC, bs + (size_t)l * HIDC);
    }
    k_pool<<<N_GRAPHSC * 4, 256, 0, stream>>>(xb, gstart, hg);
    k_readout<<<N_GRAPHSC, 256, 0, stream>>>(hg, ppos, pneg, wfc, out);
}